// Round 1
// baseline (2346.183 us; speedup 1.0000x reference)
//
#include <hip/hip_runtime.h>

#define N_NODES 10000
#define N_EDGES 640000
#define DIM_IN  128
#define DIM_HID 256
#define DIM_OUT 128

// ---------------- degree ----------------
__global__ void deg_kernel(const int* __restrict__ dst, float* __restrict__ deg, int E) {
    int e = blockIdx.x * blockDim.x + threadIdx.x;
    if (e < E) atomicAdd(&deg[dst[e]], 1.0f);
}

__global__ void invdeg_kernel(const float* __restrict__ deg, float* __restrict__ invdeg, int n) {
    int i = blockIdx.x * blockDim.x + threadIdx.x;
    if (i < n) invdeg[i] = 1.0f / fmaxf(deg[i], 1.0f);
}

// ---------------- edge scatter-add (F4 = features/4) ----------------
template<int F4>
__global__ void scatter_add_kernel(const float* __restrict__ feat, const int* __restrict__ src,
                                   const int* __restrict__ dst, float* __restrict__ agg, int E) {
    int gid = blockIdx.x * blockDim.x + threadIdx.x;
    int e = gid / F4;
    int q = gid % F4;
    if (e < E) {
        int s = src[e], d = dst[e];
        float4 v = ((const float4*)feat)[(size_t)s * F4 + q];
        float* o = agg + (size_t)d * (F4 * 4) + q * 4;
        atomicAdd(o + 0, v.x);
        atomicAdd(o + 1, v.y);
        atomicAdd(o + 2, v.z);
        atomicAdd(o + 3, v.w);
    }
}

// ---------------- fused tiled f32 GEMM ----------------
// C[M,N] = A1@B1 (+ (A2*invdeg)@B2) (+ epi*invdeg) (+ bias) (relu?)
template<bool HAS_A2, bool RELU, bool HAS_EPI>
__launch_bounds__(256)
__global__ void gemm_kernel(const float* __restrict__ A1, const float* __restrict__ B1,
                            const float* __restrict__ A2, const float* __restrict__ B2,
                            const float* __restrict__ epi,
                            const float* __restrict__ invdeg,
                            const float* __restrict__ bias,
                            float* __restrict__ C, int M, int N, int K) {
    constexpr int BM = 64, BN = 64, BK = 16;
    __shared__ float As[BM][BK + 4];   // pad: row stride 20 floats (80B, 16B-aligned)
    __shared__ float Bs[BK][BN];
    const int tid = threadIdx.x;
    const int tx = tid & 15, ty = tid >> 4;
    const int m0 = blockIdx.x * BM, n0 = blockIdx.y * BN;
    float acc[4][4] = {};

    const int npass = HAS_A2 ? 2 : 1;
    for (int pass = 0; pass < npass; ++pass) {
        const float* __restrict__ A = (HAS_A2 && pass) ? A2 : A1;
        const float* __restrict__ B = (HAS_A2 && pass) ? B2 : B1;
        for (int k0 = 0; k0 < K; k0 += BK) {
            __syncthreads();
            {   // A tile: 64 rows x 16 k
                int m = tid >> 2, kq = (tid & 3) * 4;
                int gm = m0 + m;
                float4 v = make_float4(0.f, 0.f, 0.f, 0.f);
                if (gm < M) {
                    v = *(const float4*)&A[(size_t)gm * K + k0 + kq];
                    if (HAS_A2 && pass) {
                        float s = invdeg[gm];
                        v.x *= s; v.y *= s; v.z *= s; v.w *= s;
                    }
                }
                *(float4*)&As[m][kq] = v;
            }
            {   // B tile: 16 k x 64 n
                int k = tid >> 4, nq = (tid & 15) * 4;
                *(float4*)&Bs[k][nq] = *(const float4*)&B[(size_t)(k0 + k) * N + n0 + nq];
            }
            __syncthreads();
#pragma unroll
            for (int k = 0; k < BK; ++k) {
                float a0 = As[ty * 4 + 0][k];
                float a1 = As[ty * 4 + 1][k];
                float a2 = As[ty * 4 + 2][k];
                float a3 = As[ty * 4 + 3][k];
                float4 bv = *(const float4*)&Bs[k][tx * 4];
                acc[0][0] += a0 * bv.x; acc[0][1] += a0 * bv.y; acc[0][2] += a0 * bv.z; acc[0][3] += a0 * bv.w;
                acc[1][0] += a1 * bv.x; acc[1][1] += a1 * bv.y; acc[1][2] += a1 * bv.z; acc[1][3] += a1 * bv.w;
                acc[2][0] += a2 * bv.x; acc[2][1] += a2 * bv.y; acc[2][2] += a2 * bv.z; acc[2][3] += a2 * bv.w;
                acc[3][0] += a3 * bv.x; acc[3][1] += a3 * bv.y; acc[3][2] += a3 * bv.z; acc[3][3] += a3 * bv.w;
            }
        }
    }

    // epilogue
#pragma unroll
    for (int i = 0; i < 4; ++i) {
        int gm = m0 + ty * 4 + i;
        if (gm >= M) continue;
        float invd = HAS_EPI ? invdeg[gm] : 0.f;
#pragma unroll
        for (int j = 0; j < 4; ++j) {
            int gn = n0 + tx * 4 + j;
            float v = acc[i][j];
            if (HAS_EPI) v += epi[(size_t)gm * N + gn] * invd;
            if (bias) v += bias[gn];
            if (RELU) v = fmaxf(v, 0.f);
            C[(size_t)gm * N + gn] = v;
        }
    }
}

extern "C" void kernel_launch(void* const* d_in, const int* in_sizes, int n_in,
                              void* d_out, int out_size, void* d_ws, size_t ws_size,
                              hipStream_t stream) {
    const float* x        = (const float*)d_in[0];
    const float* w_self1  = (const float*)d_in[1];
    const float* w_neigh1 = (const float*)d_in[2];
    const float* b1       = (const float*)d_in[3];
    const float* w_self2  = (const float*)d_in[4];
    const float* w_neigh2 = (const float*)d_in[5];
    const float* b2       = (const float*)d_in[6];
    const int*   src      = (const int*)d_in[7];
    const int*   dst      = (const int*)d_in[8];
    float* out = (float*)d_out;

    // workspace layout (floats)
    float* ws     = (float*)d_ws;
    float* aggx   = ws;                                        // 10000*128
    float* aggt   = aggx + (size_t)N_NODES * DIM_IN;           // 10000*128
    float* deg    = aggt + (size_t)N_NODES * DIM_OUT;          // 10000 (padded 10240)
    float* invdeg = deg + 10240;                               // 10000 (padded 10240)
    float* h      = invdeg + 10240;                            // 10000*256
    float* t      = h + (size_t)N_NODES * DIM_HID;             // 10000*128

    // zero the atomic targets (aggx | aggt | deg contiguous)
    size_t zero_floats = (size_t)N_NODES * DIM_IN + (size_t)N_NODES * DIM_OUT + 10240;
    hipMemsetAsync(aggx, 0, zero_floats * sizeof(float), stream);

    deg_kernel<<<(N_EDGES + 255) / 256, 256, 0, stream>>>(dst, deg, N_EDGES);
    invdeg_kernel<<<(N_NODES + 255) / 256, 256, 0, stream>>>(deg, invdeg, N_NODES);

    // layer-1 aggregation of x (128 features)
    scatter_add_kernel<32><<<(N_EDGES * 32) / 256, 256, 0, stream>>>(x, src, dst, aggx, N_EDGES);

    // h = relu(x@Ws1 + (aggx*invdeg)@Wn1 + b1)
    dim3 g1((N_NODES + 63) / 64, DIM_HID / 64);
    gemm_kernel<true, true, false><<<g1, 256, 0, stream>>>(
        x, w_self1, aggx, w_neigh1, nullptr, invdeg, b1, h, N_NODES, DIM_HID, DIM_IN);

    // t = h@Wn2  (project BEFORE aggregating: 128 cols instead of 256)
    dim3 g2((N_NODES + 63) / 64, DIM_OUT / 64);
    gemm_kernel<false, false, false><<<g2, 256, 0, stream>>>(
        h, w_neigh2, nullptr, nullptr, nullptr, nullptr, nullptr, t, N_NODES, DIM_OUT, DIM_HID);

    // layer-2 aggregation of t (128 features)
    scatter_add_kernel<32><<<(N_EDGES * 32) / 256, 256, 0, stream>>>(t, src, dst, aggt, N_EDGES);

    // out = h@Ws2 + aggt*invdeg + b2
    gemm_kernel<false, false, true><<<g2, 256, 0, stream>>>(
        h, w_self2, nullptr, nullptr, aggt, invdeg, b2, out, N_NODES, DIM_OUT, DIM_HID);
}

// Round 5
// 330.308 us; speedup vs baseline: 7.1030x; 7.1030x over previous
//
#include <hip/hip_runtime.h>

#define N_NODES 10000
#define N_EDGES 640000
#define DIM_IN  128
#define DIM_HID 256
#define DIM_OUT 128
#define NPAD    10240   // nodes padded to 64*160 for the single-wave scan

// ---------------- zero (own kernel: no memset node in the graph) ----------------
__global__ void zero_kernel(int* __restrict__ p, int n) {
    int i = blockIdx.x * blockDim.x + threadIdx.x;
    if (i < n) p[i] = 0;
}

// ---------------- CSR build: histogram ----------------
__global__ void hist_kernel(const int* __restrict__ dst, int* __restrict__ cnt, int E) {
    int e = blockIdx.x * blockDim.x + threadIdx.x;
    if (e < E) atomicAdd(&cnt[dst[e]], 1);
}

// ---------------- CSR build: SINGLE-WAVE exclusive scan (no __syncthreads, no LDS) ----
// 64 lanes, each owns 160 contiguous counts. Emits off, cur (=off copy), invdeg.
__global__ __launch_bounds__(64)
void scan_kernel(const int* __restrict__ cnt, int* __restrict__ off,
                 int* __restrict__ cur, float* __restrict__ invdeg) {
    const int lane = threadIdx.x;            // 0..63, one wave
    const int base = lane * (NPAD / 64);     // 160 per lane
    int s = 0;
    for (int i = 0; i < NPAD / 64; ++i) s += cnt[base + i];
    int incl = s;
#pragma unroll
    for (int d = 1; d < 64; d <<= 1) {
        int u = __shfl_up(incl, d);
        if (lane >= d) incl += u;
    }
    int run = incl - s;                      // exclusive prefix for this lane
    for (int i = 0; i < NPAD / 64; ++i) {
        int n = base + i;
        int c = cnt[n];
        off[n] = run;
        cur[n] = run;
        if (n < N_NODES) invdeg[n] = 1.0f / fmaxf((float)c, 1.0f);
        run += c;
    }
    if (lane == 63) off[NPAD] = incl;        // total = N_EDGES
}

// ---------------- CSR build: placement ----------------
__global__ void place_kernel(const int* __restrict__ src, const int* __restrict__ dst,
                             int* __restrict__ cur, int* __restrict__ sorted_src, int E) {
    int e = blockIdx.x * blockDim.x + threadIdx.x;
    if (e < E) {
        int pos = atomicAdd(&cur[dst[e]], 1);
        sorted_src[pos] = src[e];
    }
}

// ---------------- pull aggregation: one block per node, thread t = feature t ----------------
// outa[n][t] = invdeg[n] * sum_{e in CSR(n)} feat[sorted_src[e]][t]
__global__ __launch_bounds__(128)
void agg_kernel(const float* __restrict__ feat, const int* __restrict__ sorted_src,
                const int* __restrict__ off, const float* __restrict__ invdeg,
                float* __restrict__ outa) {
    const int n = blockIdx.x;
    const int tid = threadIdx.x;
    const int s0 = off[n], s1 = off[n + 1];
    __shared__ int sidx[128];
    float a0 = 0.f, a1 = 0.f, a2 = 0.f, a3 = 0.f;
    for (int base = s0; base < s1; base += 128) {
        int e = base + tid;
        sidx[tid] = (e < s1) ? sorted_src[e] : 0;
        __syncthreads();
        int c = min(128, s1 - base);
        int i = 0;
        for (; i + 4 <= c; i += 4) {
            a0 += feat[(size_t)sidx[i + 0] * 128 + tid];
            a1 += feat[(size_t)sidx[i + 1] * 128 + tid];
            a2 += feat[(size_t)sidx[i + 2] * 128 + tid];
            a3 += feat[(size_t)sidx[i + 3] * 128 + tid];
        }
        for (; i < c; ++i) a0 += feat[(size_t)sidx[i] * 128 + tid];
        __syncthreads();
    }
    outa[(size_t)n * 128 + tid] = (a0 + a1 + a2 + a3) * invdeg[n];
}

// ---------------- fused tiled f32 GEMM ----------------
// C[M,N] = A1@B1 (+ A2@B2) (+ epi) (+ bias) (relu?)
template<bool HAS_A2, bool RELU, bool HAS_EPI>
__launch_bounds__(256)
__global__ void gemm_kernel(const float* __restrict__ A1, const float* __restrict__ B1,
                            const float* __restrict__ A2, const float* __restrict__ B2,
                            const float* __restrict__ epi,
                            const float* __restrict__ bias,
                            float* __restrict__ C, int M, int N, int K) {
    constexpr int BM = 64, BN = 64, BK = 16;
    __shared__ float As[BM][BK + 4];
    __shared__ float Bs[BK][BN];
    const int tid = threadIdx.x;
    const int tx = tid & 15, ty = tid >> 4;
    const int m0 = blockIdx.x * BM, n0 = blockIdx.y * BN;
    float acc[4][4] = {};

    const int npass = HAS_A2 ? 2 : 1;
    for (int pass = 0; pass < npass; ++pass) {
        const float* __restrict__ A = (HAS_A2 && pass) ? A2 : A1;
        const float* __restrict__ B = (HAS_A2 && pass) ? B2 : B1;
        for (int k0 = 0; k0 < K; k0 += BK) {
            __syncthreads();
            {   // A tile: 64 rows x 16 k
                int m = tid >> 2, kq = (tid & 3) * 4;
                int gm = m0 + m;
                float4 v = make_float4(0.f, 0.f, 0.f, 0.f);
                if (gm < M) v = *(const float4*)&A[(size_t)gm * K + k0 + kq];
                *(float4*)&As[m][kq] = v;
            }
            {   // B tile: 16 k x 64 n
                int k = tid >> 4, nq = (tid & 15) * 4;
                *(float4*)&Bs[k][nq] = *(const float4*)&B[(size_t)(k0 + k) * N + n0 + nq];
            }
            __syncthreads();
#pragma unroll
            for (int k = 0; k < BK; ++k) {
                float a0 = As[ty * 4 + 0][k];
                float a1 = As[ty * 4 + 1][k];
                float a2 = As[ty * 4 + 2][k];
                float a3 = As[ty * 4 + 3][k];
                float4 bv = *(const float4*)&Bs[k][tx * 4];
                acc[0][0] += a0 * bv.x; acc[0][1] += a0 * bv.y; acc[0][2] += a0 * bv.z; acc[0][3] += a0 * bv.w;
                acc[1][0] += a1 * bv.x; acc[1][1] += a1 * bv.y; acc[1][2] += a1 * bv.z; acc[1][3] += a1 * bv.w;
                acc[2][0] += a2 * bv.x; acc[2][1] += a2 * bv.y; acc[2][2] += a2 * bv.z; acc[2][3] += a2 * bv.w;
                acc[3][0] += a3 * bv.x; acc[3][1] += a3 * bv.y; acc[3][2] += a3 * bv.z; acc[3][3] += a3 * bv.w;
            }
        }
    }

#pragma unroll
    for (int i = 0; i < 4; ++i) {
        int gm = m0 + ty * 4 + i;
        if (gm >= M) continue;
#pragma unroll
        for (int j = 0; j < 4; ++j) {
            int gn = n0 + tx * 4 + j;
            float v = acc[i][j];
            if (HAS_EPI) v += epi[(size_t)gm * N + gn];
            if (bias) v += bias[gn];
            if (RELU) v = fmaxf(v, 0.f);
            C[(size_t)gm * N + gn] = v;
        }
    }
}

extern "C" void kernel_launch(void* const* d_in, const int* in_sizes, int n_in,
                              void* d_out, int out_size, void* d_ws, size_t ws_size,
                              hipStream_t stream) {
    const float* x        = (const float*)d_in[0];
    const float* w_self1  = (const float*)d_in[1];
    const float* w_neigh1 = (const float*)d_in[2];
    const float* b1       = (const float*)d_in[3];
    const float* w_self2  = (const float*)d_in[4];
    const float* w_neigh2 = (const float*)d_in[5];
    const float* b2       = (const float*)d_in[6];
    const int*   src      = (const int*)d_in[7];
    const int*   dst      = (const int*)d_in[8];
    float* out = (float*)d_out;

    // workspace layout
    char* p = (char*)d_ws;
    int*   cnt        = (int*)p;                 p += NPAD * sizeof(int);
    int*   off        = (int*)p;                 p += (NPAD + 1) * sizeof(int) + 4;  // keep 8B align
    int*   cur        = (int*)p;                 p += NPAD * sizeof(int);
    int*   sorted_src = (int*)p;                 p += N_EDGES * sizeof(int);
    float* invdeg     = (float*)p;               p += NPAD * sizeof(float);
    float* aggbuf     = (float*)p;               p += (size_t)N_NODES * 128 * sizeof(float); // shared by both layers
    float* h          = (float*)p;               p += (size_t)N_NODES * DIM_HID * sizeof(float);
    float* t          = (float*)p;               p += (size_t)N_NODES * DIM_OUT * sizeof(float);

    // ---- CSR build ----
    zero_kernel<<<(NPAD + 255) / 256, 256, 0, stream>>>(cnt, NPAD);
    hist_kernel<<<(N_EDGES + 255) / 256, 256, 0, stream>>>(dst, cnt, N_EDGES);
    scan_kernel<<<1, 64, 0, stream>>>(cnt, off, cur, invdeg);
    place_kernel<<<(N_EDGES + 255) / 256, 256, 0, stream>>>(src, dst, cur, sorted_src, N_EDGES);

    // ---- layer 1 ----
    agg_kernel<<<N_NODES, 128, 0, stream>>>(x, sorted_src, off, invdeg, aggbuf);
    dim3 g1((N_NODES + 63) / 64, DIM_HID / 64);
    gemm_kernel<true, true, false><<<g1, 256, 0, stream>>>(
        x, w_self1, aggbuf, w_neigh1, nullptr, b1, h, N_NODES, DIM_HID, DIM_IN);

    // ---- layer 2 (project before aggregating: mean_agg(h@W) == mean_agg(h)@W) ----
    dim3 g2((N_NODES + 63) / 64, DIM_OUT / 64);
    gemm_kernel<false, false, false><<<g2, 256, 0, stream>>>(
        h, w_neigh2, nullptr, nullptr, nullptr, nullptr, t, N_NODES, DIM_OUT, DIM_HID);
    agg_kernel<<<N_NODES, 128, 0, stream>>>(t, sorted_src, off, invdeg, aggbuf);
    gemm_kernel<false, false, true><<<g2, 256, 0, stream>>>(
        h, w_self2, nullptr, nullptr, aggbuf, b2, out, N_NODES, DIM_OUT, DIM_HID);
}

// Round 6
// 279.680 us; speedup vs baseline: 8.3888x; 1.1810x over previous
//
#include <hip/hip_runtime.h>

#define N_NODES 10000
#define N_EDGES 640000
#define DIM_IN  128
#define DIM_HID 256
#define DIM_OUT 128
#define NPAD    10240   // nodes padded to 64*160 for the single-wave scan

typedef __attribute__((ext_vector_type(8))) short bf16x8;
typedef __attribute__((ext_vector_type(4))) float f32x4;

__device__ __forceinline__ unsigned short f2bf(float f) {
    unsigned int u = __float_as_uint(f);
    return (unsigned short)((u + 0x7fffu + ((u >> 16) & 1u)) >> 16);   // RNE
}
__device__ __forceinline__ float bf2f(unsigned short h) {
    return __uint_as_float(((unsigned int)h) << 16);
}
__device__ __forceinline__ float bflo(unsigned int u) { return __uint_as_float(u << 16); }
__device__ __forceinline__ float bfhi(unsigned int u) { return __uint_as_float(u & 0xffff0000u); }

// ---------------- zero ----------------
__global__ void zero_kernel(int* __restrict__ p, int n) {
    int i = blockIdx.x * blockDim.x + threadIdx.x;
    if (i < n) p[i] = 0;
}

// ---------------- CSR build: histogram ----------------
__global__ void hist_kernel(const int* __restrict__ dst, int* __restrict__ cnt, int E) {
    int e = blockIdx.x * blockDim.x + threadIdx.x;
    if (e < E) atomicAdd(&cnt[dst[e]], 1);
}

// ---------------- CSR build: single-wave scan (no barriers, no LDS) ----------------
__global__ __launch_bounds__(64)
void scan_kernel(const int* __restrict__ cnt, int* __restrict__ off,
                 int* __restrict__ cur, float* __restrict__ invdeg) {
    const int lane = threadIdx.x;
    const int base = lane * (NPAD / 64);
    int s = 0;
    for (int i = 0; i < NPAD / 64; ++i) s += cnt[base + i];
    int incl = s;
#pragma unroll
    for (int d = 1; d < 64; d <<= 1) {
        int u = __shfl_up(incl, d);
        if (lane >= d) incl += u;
    }
    int run = incl - s;
    for (int i = 0; i < NPAD / 64; ++i) {
        int n = base + i;
        int c = cnt[n];
        off[n] = run;
        cur[n] = run;
        if (n < N_NODES) invdeg[n] = 1.0f / fmaxf((float)c, 1.0f);
        run += c;
    }
    if (lane == 63) off[NPAD] = incl;
}

// ---------------- CSR build: placement ----------------
__global__ void place_kernel(const int* __restrict__ src, const int* __restrict__ dst,
                             int* __restrict__ cur, int* __restrict__ sorted_src, int E) {
    int e = blockIdx.x * blockDim.x + threadIdx.x;
    if (e < E) {
        int pos = atomicAdd(&cur[dst[e]], 1);
        sorted_src[pos] = src[e];
    }
}

// ---------------- f32 -> bf16 convert (4 elems/thread) ----------------
__global__ void cvt_kernel(const float* __restrict__ in, unsigned short* __restrict__ out, int n4) {
    int i = blockIdx.x * blockDim.x + threadIdx.x;
    if (i < n4) {
        float4 v = ((const float4*)in)[i];
        ushort4 o;
        o.x = f2bf(v.x); o.y = f2bf(v.y); o.z = f2bf(v.z); o.w = f2bf(v.w);
        ((ushort4*)out)[i] = o;
    }
}

// ---------------- weight transpose+convert: W[K][N] f32 -> WT[N][K] bf16 ------------
// blockIdx.y selects the weight (0:Ws1, 1:Wn1, 2:Ws2, 3:Wn2). 32768 elems each.
__global__ void wtrans_kernel(const float* __restrict__ w1s, const float* __restrict__ w1n,
                              const float* __restrict__ w2s, const float* __restrict__ w2n,
                              unsigned short* __restrict__ o1s, unsigned short* __restrict__ o1n,
                              unsigned short* __restrict__ o2s, unsigned short* __restrict__ o2n) {
    int which = blockIdx.y;
    const float* w = (which == 0) ? w1s : (which == 1) ? w1n : (which == 2) ? w2s : w2n;
    unsigned short* o = (which == 0) ? o1s : (which == 1) ? o1n : (which == 2) ? o2s : o2n;
    int K = (which < 2) ? DIM_IN : DIM_HID;
    int N = (which < 2) ? DIM_HID : DIM_OUT;
    int idx = blockIdx.x * blockDim.x + threadIdx.x;   // [0, 32768)
    int n = idx / K, k = idx - n * K;
    o[n * K + k] = f2bf(w[k * N + n]);
}

// ---------------- pull aggregation: 64 threads/node, 2 features/lane, bf16 in/out ----
__global__ __launch_bounds__(64)
void agg_kernel(const unsigned short* __restrict__ feat, const int* __restrict__ sorted_src,
                const int* __restrict__ off, const float* __restrict__ invdeg,
                unsigned short* __restrict__ outa) {
    const int n = blockIdx.x;
    const int lane = threadIdx.x;
    const int s0 = off[n], s1 = off[n + 1];
    __shared__ int sidx[64];
    float a0 = 0.f, b0 = 0.f, a1 = 0.f, b1 = 0.f;
    float a2 = 0.f, b2 = 0.f, a3 = 0.f, b3 = 0.f;
    for (int base = s0; base < s1; base += 64) {
        sidx[lane] = sorted_src[min(base + lane, s1 - 1)];
        __syncthreads();
        int c = min(64, s1 - base);
        int i = 0;
        for (; i + 4 <= c; i += 4) {
            unsigned int u0 = *(const unsigned int*)&feat[(size_t)sidx[i + 0] * 128 + 2 * lane];
            unsigned int u1 = *(const unsigned int*)&feat[(size_t)sidx[i + 1] * 128 + 2 * lane];
            unsigned int u2 = *(const unsigned int*)&feat[(size_t)sidx[i + 2] * 128 + 2 * lane];
            unsigned int u3 = *(const unsigned int*)&feat[(size_t)sidx[i + 3] * 128 + 2 * lane];
            a0 += bflo(u0); b0 += bfhi(u0);
            a1 += bflo(u1); b1 += bfhi(u1);
            a2 += bflo(u2); b2 += bfhi(u2);
            a3 += bflo(u3); b3 += bfhi(u3);
        }
        for (; i < c; ++i) {
            unsigned int u = *(const unsigned int*)&feat[(size_t)sidx[i] * 128 + 2 * lane];
            a0 += bflo(u); b0 += bfhi(u);
        }
        __syncthreads();
    }
    float inv = invdeg[n];
    float slo = ((a0 + a1) + (a2 + a3)) * inv;
    float shi = ((b0 + b1) + (b2 + b3)) * inv;
    unsigned int packed = (unsigned int)f2bf(slo) | ((unsigned int)f2bf(shi) << 16);
    *(unsigned int*)&outa[(size_t)n * 128 + 2 * lane] = packed;
}

// ---------------- MFMA bf16 GEMM ----------------
// C[M,N] = A1@B1T^T (+ A2@B2T^T) (+ epi) (+ bias) (relu?); BT is [N][K] bf16.
// 256 thr = 4 waves; block tile 64x64; wave w owns rows [w*16, w*16+16) x 64 cols.
// Fragment layout (m89/m91-verified): A/B frag = row(lane&15), k = (lane>>4)*8 + j;
// C/D: col = lane&15, row = (lane>>4)*4 + reg.
template<int PASSES, bool RELU, bool HAS_EPI, bool OUT_BF16>
__launch_bounds__(256)
__global__ void mfma_gemm(const unsigned short* __restrict__ A1, const unsigned short* __restrict__ B1T,
                          const unsigned short* __restrict__ A2, const unsigned short* __restrict__ B2T,
                          const unsigned short* __restrict__ epi, const float* __restrict__ bias,
                          void* __restrict__ Cout, int M, int N, int K) {
    const int tid = threadIdx.x;
    const int w = tid >> 6, lane = tid & 63;
    const int m0 = blockIdx.x * 64, n0 = blockIdx.y * 64;
    const int l15 = lane & 15;
    const int koff = (lane >> 4) * 8;
    const int rowc = min(m0 + w * 16 + l15, M - 1);

    f32x4 acc[4] = {};
#pragma unroll
    for (int pass = 0; pass < PASSES; ++pass) {
        const unsigned short* __restrict__ A  = (PASSES == 2 && pass) ? A2 : A1;
        const unsigned short* __restrict__ BT = (PASSES == 2 && pass) ? B2T : B1T;
        const unsigned short* arow = A + (size_t)rowc * K;
        for (int k0 = 0; k0 < K; k0 += 32) {
            bf16x8 af = *(const bf16x8*)(arow + k0 + koff);
#pragma unroll
            for (int f = 0; f < 4; ++f) {
                const unsigned short* brow = BT + (size_t)(n0 + f * 16 + l15) * K;
                bf16x8 bf = *(const bf16x8*)(brow + k0 + koff);
                acc[f] = __builtin_amdgcn_mfma_f32_16x16x32_bf16(af, bf, acc[f], 0, 0, 0);
            }
        }
    }

#pragma unroll
    for (int f = 0; f < 4; ++f) {
        int col = n0 + f * 16 + l15;
        float bv = bias ? bias[col] : 0.f;
#pragma unroll
        for (int r = 0; r < 4; ++r) {
            int grow = m0 + w * 16 + (lane >> 4) * 4 + r;
            if (grow < M) {
                float v = acc[f][r] + bv;
                if (HAS_EPI) v += bf2f(epi[(size_t)grow * N + col]);
                if (RELU) v = fmaxf(v, 0.f);
                if (OUT_BF16) ((unsigned short*)Cout)[(size_t)grow * N + col] = f2bf(v);
                else          ((float*)Cout)[(size_t)grow * N + col] = v;
            }
        }
    }
}

extern "C" void kernel_launch(void* const* d_in, const int* in_sizes, int n_in,
                              void* d_out, int out_size, void* d_ws, size_t ws_size,
                              hipStream_t stream) {
    const float* x        = (const float*)d_in[0];
    const float* w_self1  = (const float*)d_in[1];
    const float* w_neigh1 = (const float*)d_in[2];
    const float* b1       = (const float*)d_in[3];
    const float* w_self2  = (const float*)d_in[4];
    const float* w_neigh2 = (const float*)d_in[5];
    const float* b2       = (const float*)d_in[6];
    const int*   src      = (const int*)d_in[7];
    const int*   dst      = (const int*)d_in[8];
    float* out = (float*)d_out;

    // workspace layout, 1 KiB-aligned regions
    char* p = (char*)d_ws;
    auto alloc = [&](size_t bytes) { char* q = p; p += (bytes + 1023) & ~(size_t)1023; return q; };
    int*            cnt        = (int*)alloc(NPAD * 4);
    int*            off        = (int*)alloc((NPAD + 1) * 4);
    int*            cur        = (int*)alloc(NPAD * 4);
    int*            sorted_src = (int*)alloc((size_t)N_EDGES * 4);
    float*          invdeg     = (float*)alloc(NPAD * 4);
    unsigned short* xb         = (unsigned short*)alloc((size_t)N_NODES * DIM_IN * 2);
    unsigned short* w1sT       = (unsigned short*)alloc(DIM_IN * DIM_HID * 2);
    unsigned short* w1nT       = (unsigned short*)alloc(DIM_IN * DIM_HID * 2);
    unsigned short* w2sT       = (unsigned short*)alloc(DIM_HID * DIM_OUT * 2);
    unsigned short* w2nT       = (unsigned short*)alloc(DIM_HID * DIM_OUT * 2);
    unsigned short* aggbuf     = (unsigned short*)alloc((size_t)N_NODES * 128 * 2);
    unsigned short* h          = (unsigned short*)alloc((size_t)N_NODES * DIM_HID * 2);
    unsigned short* t          = (unsigned short*)alloc((size_t)N_NODES * DIM_OUT * 2);

    // ---- CSR build ----
    zero_kernel<<<(NPAD + 255) / 256, 256, 0, stream>>>(cnt, NPAD);
    hist_kernel<<<(N_EDGES + 255) / 256, 256, 0, stream>>>(dst, cnt, N_EDGES);
    scan_kernel<<<1, 64, 0, stream>>>(cnt, off, cur, invdeg);
    place_kernel<<<(N_EDGES + 255) / 256, 256, 0, stream>>>(src, dst, cur, sorted_src, N_EDGES);

    // ---- dtype prep ----
    cvt_kernel<<<((N_NODES * DIM_IN / 4) + 255) / 256, 256, 0, stream>>>(x, xb, N_NODES * DIM_IN / 4);
    wtrans_kernel<<<dim3(32768 / 256, 4), 256, 0, stream>>>(w_self1, w_neigh1, w_self2, w_neigh2,
                                                            w1sT, w1nT, w2sT, w2nT);

    // ---- layer 1: h = relu(x@Ws1 + agg(x)@Wn1 + b1), h in bf16 ----
    agg_kernel<<<N_NODES, 64, 0, stream>>>(xb, sorted_src, off, invdeg, aggbuf);
    mfma_gemm<2, true, false, true><<<dim3(157, DIM_HID / 64), 256, 0, stream>>>(
        xb, w1sT, aggbuf, w1nT, nullptr, b1, h, N_NODES, DIM_HID, DIM_IN);

    // ---- layer 2: out = h@Ws2 + agg(h@Wn2) + b2  (project-then-aggregate) ----
    mfma_gemm<1, false, false, true><<<dim3(157, DIM_OUT / 64), 256, 0, stream>>>(
        h, w2nT, nullptr, nullptr, nullptr, nullptr, t, N_NODES, DIM_OUT, DIM_HID);
    agg_kernel<<<N_NODES, 64, 0, stream>>>(t, sorted_src, off, invdeg, aggbuf);
    mfma_gemm<1, false, true, false><<<dim3(157, DIM_OUT / 64), 256, 0, stream>>>(
        h, w2sT, nullptr, nullptr, aggbuf, b2, out, N_NODES, DIM_OUT, DIM_HID);
}

// Round 7
// 205.891 us; speedup vs baseline: 11.3953x; 1.3584x over previous
//
#include <hip/hip_runtime.h>

#define N_NODES 10000
#define N_EDGES 640000
#define DIM_IN  128
#define DIM_HID 256
#define DIM_OUT 128
#define NPAD    10240   // NBUCK * NPB
#define NBUCK   80      // buckets; bucket = dst >> 7
#define NPB     128     // nodes per bucket
#define NBLKA   160     // edge-partition blocks
#define EPB     4000    // edges per block; NBLKA*EPB == N_EDGES

typedef __attribute__((ext_vector_type(8))) short bf16x8;
typedef __attribute__((ext_vector_type(4))) float f32x4;

__device__ __forceinline__ unsigned short f2bf(float f) {
    unsigned int u = __float_as_uint(f);
    return (unsigned short)((u + 0x7fffu + ((u >> 16) & 1u)) >> 16);   // RNE
}
__device__ __forceinline__ float bf2f(unsigned short h) {
    return __uint_as_float(((unsigned int)h) << 16);
}
__device__ __forceinline__ float bflo(unsigned int u) { return __uint_as_float(u << 16); }
__device__ __forceinline__ float bfhi(unsigned int u) { return __uint_as_float(u & 0xffff0000u); }

// ---------------- CSR 1/4: per-(block,bucket) counts, LDS histogram ----------------
__global__ __launch_bounds__(256)
void countA_kernel(const int* __restrict__ dst, int* __restrict__ cntAT) {
    __shared__ int c[NBUCK];
    const int tid = threadIdx.x, blk = blockIdx.x;
    if (tid < NBUCK) c[tid] = 0;
    __syncthreads();
    const int e0 = blk * EPB;
    for (int i = tid; i < EPB; i += 256) atomicAdd(&c[dst[e0 + i] >> 7], 1);
    __syncthreads();
    if (tid < NBUCK) cntAT[tid * NBLKA + blk] = c[tid];   // transposed: bucket-major
}

// ---------------- CSR 2/4: single-wave scan of 12800 run counts ----------------
__global__ __launch_bounds__(64)
void scanB_kernel(const int* __restrict__ cntAT, int* __restrict__ runoffT) {
    const int lane = threadIdx.x;
    const int base = lane * (NBUCK * NBLKA / 64);     // 200 per lane
    int s = 0;
    for (int i = 0; i < NBUCK * NBLKA / 64; ++i) s += cntAT[base + i];
    int incl = s;
#pragma unroll
    for (int d = 1; d < 64; d <<= 1) {
        int u = __shfl_up(incl, d);
        if (lane >= d) incl += u;
    }
    int run = incl - s;
    for (int i = 0; i < NBUCK * NBLKA / 64; ++i) {
        runoffT[base + i] = run;
        run += cntAT[base + i];
    }
}

// ---------------- CSR 3/4: scatter edges into bucket-grouped arrays ----------------
// Each (blk,bucket) run is contiguous; cursors live in LDS (no global atomics).
__global__ __launch_bounds__(256)
void scatterA_kernel(const int* __restrict__ src, const int* __restrict__ dst,
                     const int* __restrict__ runoffT,
                     int* __restrict__ srcb, int* __restrict__ dstb) {
    __shared__ int cur[NBUCK];
    const int tid = threadIdx.x, blk = blockIdx.x;
    if (tid < NBUCK) cur[tid] = runoffT[tid * NBLKA + blk];
    __syncthreads();
    const int e0 = blk * EPB;
    for (int i = tid; i < EPB; i += 256) {
        int s = src[e0 + i], d = dst[e0 + i];
        int pos = atomicAdd(&cur[d >> 7], 1);
        srcb[pos] = s;
        dstb[pos] = d;
    }
}

// ---------------- CSR 4/4: per-bucket node grouping; off/invdeg/sorted_src --------
// One block owns bucket b exclusively: its 128 nodes, its contiguous edge range,
// its contiguous sorted_src output range (single-writer -> no cross-XCD line sharing).
__global__ __launch_bounds__(256)
void binB_kernel(const int* __restrict__ srcb, const int* __restrict__ dstb,
                 const int* __restrict__ runoffT, int* __restrict__ off,
                 float* __restrict__ invdeg, int* __restrict__ sorted_src) {
    __shared__ int cnt[NPB];
    __shared__ int curs[NPB];
    const int tid = threadIdx.x, b = blockIdx.x;
    const int base = runoffT[b * NBLKA];
    const int end  = (b == NBUCK - 1) ? N_EDGES : runoffT[(b + 1) * NBLKA];
    if (tid < NPB) cnt[tid] = 0;
    __syncthreads();
    for (int e = base + tid; e < end; e += 256) atomicAdd(&cnt[dstb[e] & (NPB - 1)], 1);
    __syncthreads();
    if (tid < 64) {   // wave-0 shfl scan of 128 counts (2 per lane)
        int c0 = cnt[tid * 2], c1 = cnt[tid * 2 + 1];
        int s = c0 + c1;
        int incl = s;
#pragma unroll
        for (int d = 1; d < 64; d <<= 1) {
            int u = __shfl_up(incl, d);
            if (tid >= d) incl += u;
        }
        int run = incl - s;
        curs[tid * 2] = run;
        curs[tid * 2 + 1] = run + c0;
    }
    __syncthreads();
    if (tid < NPB) {
        int n = b * NPB + tid;
        off[n] = base + curs[tid];
        if (n < N_NODES) invdeg[n] = 1.0f / fmaxf((float)cnt[tid], 1.0f);
        if (n == NPAD - 1) off[NPAD] = N_EDGES;
    }
    __syncthreads();
    for (int e = base + tid; e < end; e += 256) {
        int n = dstb[e] & (NPB - 1);
        int pos = base + atomicAdd(&curs[n], 1);
        sorted_src[pos] = srcb[e];
    }
}

// ---------------- f32 -> bf16 convert (4 elems/thread) ----------------
__global__ void cvt_kernel(const float* __restrict__ in, unsigned short* __restrict__ out, int n4) {
    int i = blockIdx.x * blockDim.x + threadIdx.x;
    if (i < n4) {
        float4 v = ((const float4*)in)[i];
        ushort4 o;
        o.x = f2bf(v.x); o.y = f2bf(v.y); o.z = f2bf(v.z); o.w = f2bf(v.w);
        ((ushort4*)out)[i] = o;
    }
}

// ---------------- weight transpose+convert: W[K][N] f32 -> WT[N][K] bf16 ------------
__global__ void wtrans_kernel(const float* __restrict__ w1s, const float* __restrict__ w1n,
                              const float* __restrict__ w2s, const float* __restrict__ w2n,
                              unsigned short* __restrict__ o1s, unsigned short* __restrict__ o1n,
                              unsigned short* __restrict__ o2s, unsigned short* __restrict__ o2n) {
    int which = blockIdx.y;
    const float* w = (which == 0) ? w1s : (which == 1) ? w1n : (which == 2) ? w2s : w2n;
    unsigned short* o = (which == 0) ? o1s : (which == 1) ? o1n : (which == 2) ? o2s : o2n;
    int K = (which < 2) ? DIM_IN : DIM_HID;
    int N = (which < 2) ? DIM_HID : DIM_OUT;
    int idx = blockIdx.x * blockDim.x + threadIdx.x;
    int n = idx / K, k = idx - n * K;
    o[n * K + k] = f2bf(w[k * N + n]);
}

// ---------------- pull aggregation: 64 threads/node, 2 features/lane, bf16 in/out ----
__global__ __launch_bounds__(64)
void agg_kernel(const unsigned short* __restrict__ feat, const int* __restrict__ sorted_src,
                const int* __restrict__ off, const float* __restrict__ invdeg,
                unsigned short* __restrict__ outa) {
    const int n = blockIdx.x;
    const int lane = threadIdx.x;
    const int s0 = off[n], s1 = off[n + 1];
    __shared__ int sidx[64];
    float a0 = 0.f, b0 = 0.f, a1 = 0.f, b1 = 0.f;
    float a2 = 0.f, b2 = 0.f, a3 = 0.f, b3 = 0.f;
    for (int base = s0; base < s1; base += 64) {
        sidx[lane] = sorted_src[min(base + lane, s1 - 1)];
        __syncthreads();
        int c = min(64, s1 - base);
        int i = 0;
        for (; i + 4 <= c; i += 4) {
            unsigned int u0 = *(const unsigned int*)&feat[(size_t)sidx[i + 0] * 128 + 2 * lane];
            unsigned int u1 = *(const unsigned int*)&feat[(size_t)sidx[i + 1] * 128 + 2 * lane];
            unsigned int u2 = *(const unsigned int*)&feat[(size_t)sidx[i + 2] * 128 + 2 * lane];
            unsigned int u3 = *(const unsigned int*)&feat[(size_t)sidx[i + 3] * 128 + 2 * lane];
            a0 += bflo(u0); b0 += bfhi(u0);
            a1 += bflo(u1); b1 += bfhi(u1);
            a2 += bflo(u2); b2 += bfhi(u2);
            a3 += bflo(u3); b3 += bfhi(u3);
        }
        for (; i < c; ++i) {
            unsigned int u = *(const unsigned int*)&feat[(size_t)sidx[i] * 128 + 2 * lane];
            a0 += bflo(u); b0 += bfhi(u);
        }
        __syncthreads();
    }
    float inv = invdeg[n];
    float slo = ((a0 + a1) + (a2 + a3)) * inv;
    float shi = ((b0 + b1) + (b2 + b3)) * inv;
    unsigned int packed = (unsigned int)f2bf(slo) | ((unsigned int)f2bf(shi) << 16);
    *(unsigned int*)&outa[(size_t)n * 128 + 2 * lane] = packed;
}

// ---------------- MFMA bf16 GEMM (layouts m89/m91-verified) ----------------
template<int PASSES, bool RELU, bool HAS_EPI, bool OUT_BF16>
__launch_bounds__(256)
__global__ void mfma_gemm(const unsigned short* __restrict__ A1, const unsigned short* __restrict__ B1T,
                          const unsigned short* __restrict__ A2, const unsigned short* __restrict__ B2T,
                          const unsigned short* __restrict__ epi, const float* __restrict__ bias,
                          void* __restrict__ Cout, int M, int N, int K) {
    const int tid = threadIdx.x;
    const int w = tid >> 6, lane = tid & 63;
    const int m0 = blockIdx.x * 64, n0 = blockIdx.y * 64;
    const int l15 = lane & 15;
    const int koff = (lane >> 4) * 8;
    const int rowc = min(m0 + w * 16 + l15, M - 1);

    f32x4 acc[4] = {};
#pragma unroll
    for (int pass = 0; pass < PASSES; ++pass) {
        const unsigned short* __restrict__ A  = (PASSES == 2 && pass) ? A2 : A1;
        const unsigned short* __restrict__ BT = (PASSES == 2 && pass) ? B2T : B1T;
        const unsigned short* arow = A + (size_t)rowc * K;
        for (int k0 = 0; k0 < K; k0 += 32) {
            bf16x8 af = *(const bf16x8*)(arow + k0 + koff);
#pragma unroll
            for (int f = 0; f < 4; ++f) {
                const unsigned short* brow = BT + (size_t)(n0 + f * 16 + l15) * K;
                bf16x8 bf = *(const bf16x8*)(brow + k0 + koff);
                acc[f] = __builtin_amdgcn_mfma_f32_16x16x32_bf16(af, bf, acc[f], 0, 0, 0);
            }
        }
    }

#pragma unroll
    for (int f = 0; f < 4; ++f) {
        int col = n0 + f * 16 + l15;
        float bv = bias ? bias[col] : 0.f;
#pragma unroll
        for (int r = 0; r < 4; ++r) {
            int grow = m0 + w * 16 + (lane >> 4) * 4 + r;
            if (grow < M) {
                float v = acc[f][r] + bv;
                if (HAS_EPI) v += bf2f(epi[(size_t)grow * N + col]);
                if (RELU) v = fmaxf(v, 0.f);
                if (OUT_BF16) ((unsigned short*)Cout)[(size_t)grow * N + col] = f2bf(v);
                else          ((float*)Cout)[(size_t)grow * N + col] = v;
            }
        }
    }
}

extern "C" void kernel_launch(void* const* d_in, const int* in_sizes, int n_in,
                              void* d_out, int out_size, void* d_ws, size_t ws_size,
                              hipStream_t stream) {
    const float* x        = (const float*)d_in[0];
    const float* w_self1  = (const float*)d_in[1];
    const float* w_neigh1 = (const float*)d_in[2];
    const float* b1       = (const float*)d_in[3];
    const float* w_self2  = (const float*)d_in[4];
    const float* w_neigh2 = (const float*)d_in[5];
    const float* b2       = (const float*)d_in[6];
    const int*   src      = (const int*)d_in[7];
    const int*   dst      = (const int*)d_in[8];
    float* out = (float*)d_out;

    // workspace layout, 1 KiB-aligned regions
    char* p = (char*)d_ws;
    auto alloc = [&](size_t bytes) { char* q = p; p += (bytes + 1023) & ~(size_t)1023; return q; };
    int*            cntAT      = (int*)alloc(NBUCK * NBLKA * 4);
    int*            runoffT    = (int*)alloc(NBUCK * NBLKA * 4);
    int*            srcb       = (int*)alloc((size_t)N_EDGES * 4);
    int*            dstb       = (int*)alloc((size_t)N_EDGES * 4);
    int*            off        = (int*)alloc((NPAD + 1) * 4);
    int*            sorted_src = (int*)alloc((size_t)N_EDGES * 4);
    float*          invdeg     = (float*)alloc(NPAD * 4);
    unsigned short* xb         = (unsigned short*)alloc((size_t)N_NODES * DIM_IN * 2);
    unsigned short* w1sT       = (unsigned short*)alloc(DIM_IN * DIM_HID * 2);
    unsigned short* w1nT       = (unsigned short*)alloc(DIM_IN * DIM_HID * 2);
    unsigned short* w2sT       = (unsigned short*)alloc(DIM_HID * DIM_OUT * 2);
    unsigned short* w2nT       = (unsigned short*)alloc(DIM_HID * DIM_OUT * 2);
    unsigned short* aggbuf     = (unsigned short*)alloc((size_t)N_NODES * 128 * 2);
    unsigned short* h          = (unsigned short*)alloc((size_t)N_NODES * DIM_HID * 2);
    unsigned short* t          = (unsigned short*)alloc((size_t)N_NODES * DIM_OUT * 2);

    // ---- CSR build (atomic-free, exclusive-ownership) ----
    countA_kernel  <<<NBLKA, 256, 0, stream>>>(dst, cntAT);
    scanB_kernel   <<<1, 64, 0, stream>>>(cntAT, runoffT);
    scatterA_kernel<<<NBLKA, 256, 0, stream>>>(src, dst, runoffT, srcb, dstb);
    binB_kernel    <<<NBUCK, 256, 0, stream>>>(srcb, dstb, runoffT, off, invdeg, sorted_src);

    // ---- dtype prep ----
    cvt_kernel<<<((N_NODES * DIM_IN / 4) + 255) / 256, 256, 0, stream>>>(x, xb, N_NODES * DIM_IN / 4);
    wtrans_kernel<<<dim3(32768 / 256, 4), 256, 0, stream>>>(w_self1, w_neigh1, w_self2, w_neigh2,
                                                            w1sT, w1nT, w2sT, w2nT);

    // ---- layer 1: h = relu(x@Ws1 + agg(x)@Wn1 + b1) ----
    agg_kernel<<<N_NODES, 64, 0, stream>>>(xb, sorted_src, off, invdeg, aggbuf);
    mfma_gemm<2, true, false, true><<<dim3(157, DIM_HID / 64), 256, 0, stream>>>(
        xb, w1sT, aggbuf, w1nT, nullptr, b1, h, N_NODES, DIM_HID, DIM_IN);

    // ---- layer 2: out = h@Ws2 + agg(h@Wn2) + b2 (project-then-aggregate) ----
    mfma_gemm<1, false, false, true><<<dim3(157, DIM_OUT / 64), 256, 0, stream>>>(
        h, w2nT, nullptr, nullptr, nullptr, nullptr, t, N_NODES, DIM_OUT, DIM_HID);
    agg_kernel<<<N_NODES, 64, 0, stream>>>(t, sorted_src, off, invdeg, aggbuf);
    mfma_gemm<1, false, true, false><<<dim3(157, DIM_OUT / 64), 256, 0, stream>>>(
        h, w2sT, nullptr, nullptr, aggbuf, b2, out, N_NODES, DIM_OUT, DIM_HID);
}

// Round 11
// 204.833 us; speedup vs baseline: 11.4541x; 1.0052x over previous
//
#include <hip/hip_runtime.h>

#define N_NODES 10000
#define N_EDGES 640000
#define DIM_IN  128
#define DIM_HID 256
#define DIM_OUT 128
#define NPAD    10240   // NBUCK * NPB
#define NBUCK   80      // buckets; bucket = dst >> 7
#define NPB     128     // nodes per bucket
#define NBLKA   160     // edge-partition blocks
#define EPB     4000    // edges per block; NBLKA*EPB == N_EDGES

typedef __attribute__((ext_vector_type(8))) short bf16x8;
typedef __attribute__((ext_vector_type(4))) float f32x4;

__device__ __forceinline__ unsigned short f2bf(float f) {
    unsigned int u = __float_as_uint(f);
    return (unsigned short)((u + 0x7fffu + ((u >> 16) & 1u)) >> 16);   // RNE
}
__device__ __forceinline__ float bf2f(unsigned short h) {
    return __uint_as_float(((unsigned int)h) << 16);
}
__device__ __forceinline__ float bflo(unsigned int u) { return __uint_as_float(u << 16); }
__device__ __forceinline__ float bfhi(unsigned int u) { return __uint_as_float(u & 0xffff0000u); }

// ---------------- CSR 1/4: per-(block,bucket) counts, LDS histogram ----------------
__global__ __launch_bounds__(256)
void countA_kernel(const int* __restrict__ dst, int* __restrict__ cntAT) {
    __shared__ int c[NBUCK];
    const int tid = threadIdx.x, blk = blockIdx.x;
    if (tid < NBUCK) c[tid] = 0;
    __syncthreads();
    const int e0 = blk * EPB;
    for (int i = tid; i < EPB; i += 256) atomicAdd(&c[dst[e0 + i] >> 7], 1);
    __syncthreads();
    if (tid < NBUCK) cntAT[tid * NBLKA + blk] = c[tid];   // transposed: bucket-major
}

// ---------------- CSR 2/4: single-wave scan of 12800 run counts ----------------
__global__ __launch_bounds__(64)
void scanB_kernel(const int* __restrict__ cntAT, int* __restrict__ runoffT) {
    const int lane = threadIdx.x;
    const int base = lane * (NBUCK * NBLKA / 64);     // 200 per lane
    int s = 0;
    for (int i = 0; i < NBUCK * NBLKA / 64; ++i) s += cntAT[base + i];
    int incl = s;
#pragma unroll
    for (int d = 1; d < 64; d <<= 1) {
        int u = __shfl_up(incl, d);
        if (lane >= d) incl += u;
    }
    int run = incl - s;
    for (int i = 0; i < NBUCK * NBLKA / 64; ++i) {
        runoffT[base + i] = run;
        run += cntAT[base + i];
    }
}

// ---------------- CSR 3/4: scatter edges into bucket-grouped arrays ----------------
__global__ __launch_bounds__(256)
void scatterA_kernel(const int* __restrict__ src, const int* __restrict__ dst,
                     const int* __restrict__ runoffT,
                     int* __restrict__ srcb, int* __restrict__ dstb) {
    __shared__ int cur[NBUCK];
    const int tid = threadIdx.x, blk = blockIdx.x;
    if (tid < NBUCK) cur[tid] = runoffT[tid * NBLKA + blk];
    __syncthreads();
    const int e0 = blk * EPB;
    for (int i = tid; i < EPB; i += 256) {
        int s = src[e0 + i], d = dst[e0 + i];
        int pos = atomicAdd(&cur[d >> 7], 1);
        srcb[pos] = s;
        dstb[pos] = d;
    }
}

// ---------------- CSR 4/4: per-bucket node grouping; off/invdeg/sorted_src --------
__global__ __launch_bounds__(256)
void binB_kernel(const int* __restrict__ srcb, const int* __restrict__ dstb,
                 const int* __restrict__ runoffT, int* __restrict__ off,
                 float* __restrict__ invdeg, int* __restrict__ sorted_src) {
    __shared__ int cnt[NPB];
    __shared__ int curs[NPB];
    const int tid = threadIdx.x, b = blockIdx.x;
    const int base = runoffT[b * NBLKA];
    const int end  = (b == NBUCK - 1) ? N_EDGES : runoffT[(b + 1) * NBLKA];
    if (tid < NPB) cnt[tid] = 0;
    __syncthreads();
    for (int e = base + tid; e < end; e += 256) atomicAdd(&cnt[dstb[e] & (NPB - 1)], 1);
    __syncthreads();
    if (tid < 64) {   // wave-0 shfl scan of 128 counts (2 per lane)
        int c0 = cnt[tid * 2], c1 = cnt[tid * 2 + 1];
        int s = c0 + c1;
        int incl = s;
#pragma unroll
        for (int d = 1; d < 64; d <<= 1) {
            int u = __shfl_up(incl, d);
            if (tid >= d) incl += u;
        }
        int run = incl - s;
        curs[tid * 2] = run;
        curs[tid * 2 + 1] = run + c0;
    }
    __syncthreads();
    if (tid < NPB) {
        int n = b * NPB + tid;
        off[n] = base + curs[tid];
        if (n < N_NODES) invdeg[n] = 1.0f / fmaxf((float)cnt[tid], 1.0f);
        if (n == NPAD - 1) off[NPAD] = N_EDGES;
    }
    __syncthreads();
    for (int e = base + tid; e < end; e += 256) {
        int n = dstb[e] & (NPB - 1);
        int pos = base + atomicAdd(&curs[n], 1);
        sorted_src[pos] = srcb[e];
    }
}

// ---------------- prep: x f32->bf16 (blocks 0..1249) + 4x weight transpose ----------
__global__ __launch_bounds__(256)
void prep_kernel(const float* __restrict__ x, unsigned short* __restrict__ xb,
                 const float* __restrict__ w1s, const float* __restrict__ w1n,
                 const float* __restrict__ w2s, const float* __restrict__ w2n,
                 unsigned short* __restrict__ o1s, unsigned short* __restrict__ o1n,
                 unsigned short* __restrict__ o2s, unsigned short* __restrict__ o2n) {
    const int tid = threadIdx.x, blk = blockIdx.x;
    if (blk < 1250) {                      // cvt: 320000 float4 groups
        int i = blk * 256 + tid;
        float4 v = ((const float4*)x)[i];
        ushort4 o;
        o.x = f2bf(v.x); o.y = f2bf(v.y); o.z = f2bf(v.z); o.w = f2bf(v.w);
        ((ushort4*)xb)[i] = o;
    } else {                               // wtrans: 4 weights x 128 blocks
        int which = (blk - 1250) >> 7;
        const float* w = (which == 0) ? w1s : (which == 1) ? w1n : (which == 2) ? w2s : w2n;
        unsigned short* o = (which == 0) ? o1s : (which == 1) ? o1n : (which == 2) ? o2s : o2n;
        int K = (which < 2) ? DIM_IN : DIM_HID;
        int N = (which < 2) ? DIM_HID : DIM_OUT;
        int idx = ((blk - 1250) & 127) * 256 + tid;
        int n = idx / K, k = idx - n * K;
        o[n * K + k] = f2bf(w[k * N + n]);
    }
}

// ---------------- pull aggregation (R7-proven v1.5): 64 thr/node, 2 feat/lane -------
__global__ __launch_bounds__(64)
void agg_kernel(const unsigned short* __restrict__ feat, const int* __restrict__ sorted_src,
                const int* __restrict__ off, const float* __restrict__ invdeg,
                unsigned short* __restrict__ outa) {
    const int n = blockIdx.x;
    const int lane = threadIdx.x;
    const int s0 = off[n], s1 = off[n + 1];
    __shared__ int sidx[64];
    float a0 = 0.f, b0 = 0.f, a1 = 0.f, b1 = 0.f;
    float a2 = 0.f, b2 = 0.f, a3 = 0.f, b3 = 0.f;
    for (int base = s0; base < s1; base += 64) {
        sidx[lane] = sorted_src[min(base + lane, s1 - 1)];
        __syncthreads();
        int c = min(64, s1 - base);
        int i = 0;
        for (; i + 4 <= c; i += 4) {
            unsigned int u0 = *(const unsigned int*)&feat[(size_t)sidx[i + 0] * 128 + 2 * lane];
            unsigned int u1 = *(const unsigned int*)&feat[(size_t)sidx[i + 1] * 128 + 2 * lane];
            unsigned int u2 = *(const unsigned int*)&feat[(size_t)sidx[i + 2] * 128 + 2 * lane];
            unsigned int u3 = *(const unsigned int*)&feat[(size_t)sidx[i + 3] * 128 + 2 * lane];
            a0 += bflo(u0); b0 += bfhi(u0);
            a1 += bflo(u1); b1 += bfhi(u1);
            a2 += bflo(u2); b2 += bfhi(u2);
            a3 += bflo(u3); b3 += bfhi(u3);
        }
        for (; i < c; ++i) {
            unsigned int u = *(const unsigned int*)&feat[(size_t)sidx[i] * 128 + 2 * lane];
            a0 += bflo(u); b0 += bfhi(u);
        }
        __syncthreads();
    }
    float inv = invdeg[n];
    float slo = ((a0 + a1) + (a2 + a3)) * inv;
    float shi = ((b0 + b1) + (b2 + b3)) * inv;
    unsigned int packed = (unsigned int)f2bf(slo) | ((unsigned int)f2bf(shi) << 16);
    *(unsigned int*)&outa[(size_t)n * 128 + 2 * lane] = packed;
}

// ---------------- MFMA bf16 GEMM (R7-proven; layouts m89/m91-verified) ----------------
// C[M,N] = A1@B1T^T (+ A2@B2T^T) (+ epi) (+ bias) (relu?); BT is [N][K] bf16.
template<int PASSES, bool RELU, bool HAS_EPI, bool OUT_BF16>
__launch_bounds__(256)
__global__ void mfma_gemm(const unsigned short* __restrict__ A1, const unsigned short* __restrict__ B1T,
                          const unsigned short* __restrict__ A2, const unsigned short* __restrict__ B2T,
                          const unsigned short* __restrict__ epi, const float* __restrict__ bias,
                          void* __restrict__ Cout, int M, int N, int K) {
    const int tid = threadIdx.x;
    const int w = tid >> 6, lane = tid & 63;
    const int m0 = blockIdx.x * 64, n0 = blockIdx.y * 64;
    const int l15 = lane & 15;
    const int koff = (lane >> 4) * 8;
    const int rowc = min(m0 + w * 16 + l15, M - 1);

    f32x4 acc[4] = {};
#pragma unroll
    for (int pass = 0; pass < PASSES; ++pass) {
        const unsigned short* __restrict__ A  = (PASSES == 2 && pass) ? A2 : A1;
        const unsigned short* __restrict__ BT = (PASSES == 2 && pass) ? B2T : B1T;
        const unsigned short* arow = A + (size_t)rowc * K;
        for (int k0 = 0; k0 < K; k0 += 32) {
            bf16x8 af = *(const bf16x8*)(arow + k0 + koff);
#pragma unroll
            for (int f = 0; f < 4; ++f) {
                const unsigned short* brow = BT + (size_t)(n0 + f * 16 + l15) * K;
                bf16x8 bfr = *(const bf16x8*)(brow + k0 + koff);
                acc[f] = __builtin_amdgcn_mfma_f32_16x16x32_bf16(af, bfr, acc[f], 0, 0, 0);
            }
        }
    }

#pragma unroll
    for (int f = 0; f < 4; ++f) {
        int col = n0 + f * 16 + l15;
        float bv = bias ? bias[col] : 0.f;
#pragma unroll
        for (int r = 0; r < 4; ++r) {
            int grow = m0 + w * 16 + (lane >> 4) * 4 + r;
            if (grow < M) {
                float v = acc[f][r] + bv;
                if (HAS_EPI) v += bf2f(epi[(size_t)grow * N + col]);
                if (RELU) v = fmaxf(v, 0.f);
                if (OUT_BF16) ((unsigned short*)Cout)[(size_t)grow * N + col] = f2bf(v);
                else          ((float*)Cout)[(size_t)grow * N + col] = v;
            }
        }
    }
}

extern "C" void kernel_launch(void* const* d_in, const int* in_sizes, int n_in,
                              void* d_out, int out_size, void* d_ws, size_t ws_size,
                              hipStream_t stream) {
    const float* x        = (const float*)d_in[0];
    const float* w_self1  = (const float*)d_in[1];
    const float* w_neigh1 = (const float*)d_in[2];
    const float* b1       = (const float*)d_in[3];
    const float* w_self2  = (const float*)d_in[4];
    const float* w_neigh2 = (const float*)d_in[5];
    const float* b2       = (const float*)d_in[6];
    const int*   src      = (const int*)d_in[7];
    const int*   dst      = (const int*)d_in[8];
    float* out = (float*)d_out;

    // workspace layout, 1 KiB-aligned regions
    char* p = (char*)d_ws;
    auto alloc = [&](size_t bytes) { char* q = p; p += (bytes + 1023) & ~(size_t)1023; return q; };
    int*            cntAT      = (int*)alloc(NBUCK * NBLKA * 4);
    int*            runoffT    = (int*)alloc(NBUCK * NBLKA * 4);
    int*            srcb       = (int*)alloc((size_t)N_EDGES * 4);
    int*            dstb       = (int*)alloc((size_t)N_EDGES * 4);
    int*            off        = (int*)alloc((NPAD + 1) * 4);
    int*            sorted_src = (int*)alloc((size_t)N_EDGES * 4);
    float*          invdeg     = (float*)alloc(NPAD * 4);
    unsigned short* xb         = (unsigned short*)alloc((size_t)N_NODES * DIM_IN * 2);
    unsigned short* w1sT       = (unsigned short*)alloc(DIM_IN * DIM_HID * 2);
    unsigned short* w1nT       = (unsigned short*)alloc(DIM_IN * DIM_HID * 2);
    unsigned short* w2sT       = (unsigned short*)alloc(DIM_HID * DIM_OUT * 2);
    unsigned short* w2nT       = (unsigned short*)alloc(DIM_HID * DIM_OUT * 2);
    unsigned short* aggbuf     = (unsigned short*)alloc((size_t)N_NODES * 128 * 2);
    unsigned short* h          = (unsigned short*)alloc((size_t)N_NODES * DIM_HID * 2);
    unsigned short* t          = (unsigned short*)alloc((size_t)N_NODES * DIM_OUT * 2);

    // ---- CSR build (atomic-free, exclusive-ownership) ----
    countA_kernel  <<<NBLKA, 256, 0, stream>>>(dst, cntAT);
    scanB_kernel   <<<1, 64, 0, stream>>>(cntAT, runoffT);
    scatterA_kernel<<<NBLKA, 256, 0, stream>>>(src, dst, runoffT, srcb, dstb);
    binB_kernel    <<<NBUCK, 256, 0, stream>>>(srcb, dstb, runoffT, off, invdeg, sorted_src);

    // ---- dtype prep (cvt + 4 weight transposes, one kernel; formula-identical to R7) ----
    prep_kernel<<<1250 + 512, 256, 0, stream>>>(x, xb, w_self1, w_neigh1, w_self2, w_neigh2,
                                                w1sT, w1nT, w2sT, w2nT);

    // ---- layer 1: h = relu(x@Ws1 + agg(x)@Wn1 + b1) ----
    agg_kernel<<<N_NODES, 64, 0, stream>>>(xb, sorted_src, off, invdeg, aggbuf);
    mfma_gemm<2, true, false, true><<<dim3(157, DIM_HID / 64), 256, 0, stream>>>(
        xb, w1sT, aggbuf, w1nT, nullptr, b1, h, N_NODES, DIM_HID, DIM_IN);

    // ---- layer 2: t = h@Wn2; out = h@Ws2 + agg(t) + b2 (project-then-aggregate) ----
    mfma_gemm<1, false, false, true><<<dim3(157, DIM_OUT / 64), 256, 0, stream>>>(
        h, w2nT, nullptr, nullptr, nullptr, nullptr, t, N_NODES, DIM_OUT, DIM_HID);
    agg_kernel<<<N_NODES, 64, 0, stream>>>(t, sorted_src, off, invdeg, aggbuf);
    mfma_gemm<1, false, true, false><<<dim3(157, DIM_OUT / 64), 256, 0, stream>>>(
        h, w2sT, nullptr, nullptr, aggbuf, b2, out, N_NODES, DIM_OUT, DIM_HID);
}

// Round 12
// 194.311 us; speedup vs baseline: 12.0744x; 1.0542x over previous
//
#include <hip/hip_runtime.h>

#define N_NODES 10000
#define N_EDGES 640000
#define DIM_IN  128
#define DIM_HID 256
#define DIM_OUT 128
#define NPAD    10240   // NBUCK * NPB
#define NBUCK   80      // buckets; bucket = dst >> 7
#define NPB     128     // nodes per bucket
#define NBLKA   160     // edge-partition blocks
#define EPB     4000    // edges per block; NBLKA*EPB == N_EDGES

typedef __attribute__((ext_vector_type(8))) short bf16x8;
typedef __attribute__((ext_vector_type(4))) float f32x4;

__device__ __forceinline__ unsigned short f2bf(float f) {
    unsigned int u = __float_as_uint(f);
    return (unsigned short)((u + 0x7fffu + ((u >> 16) & 1u)) >> 16);   // RNE
}
__device__ __forceinline__ float bf2f(unsigned short h) {
    return __uint_as_float(((unsigned int)h) << 16);
}
__device__ __forceinline__ float bflo(unsigned int u) { return __uint_as_float(u << 16); }
__device__ __forceinline__ float bfhi(unsigned int u) { return __uint_as_float(u & 0xffff0000u); }

// ---------------- CSR 1/4: per-(block,bucket) counts, LDS histogram ----------------
__global__ __launch_bounds__(256)
void countA_kernel(const int* __restrict__ dst, int* __restrict__ cntAT) {
    __shared__ int c[NBUCK];
    const int tid = threadIdx.x, blk = blockIdx.x;
    if (tid < NBUCK) c[tid] = 0;
    __syncthreads();
    const int e0 = blk * EPB;
    for (int i = tid; i < EPB; i += 256) atomicAdd(&c[dst[e0 + i] >> 7], 1);
    __syncthreads();
    if (tid < NBUCK) cntAT[tid * NBLKA + blk] = c[tid];   // transposed: bucket-major
}

// ---------------- CSR 2/4: single-wave scan of 12800 run counts ----------------
__global__ __launch_bounds__(64)
void scanB_kernel(const int* __restrict__ cntAT, int* __restrict__ runoffT) {
    const int lane = threadIdx.x;
    const int base = lane * (NBUCK * NBLKA / 64);     // 200 per lane
    int s = 0;
    for (int i = 0; i < NBUCK * NBLKA / 64; ++i) s += cntAT[base + i];
    int incl = s;
#pragma unroll
    for (int d = 1; d < 64; d <<= 1) {
        int u = __shfl_up(incl, d);
        if (lane >= d) incl += u;
    }
    int run = incl - s;
    for (int i = 0; i < NBUCK * NBLKA / 64; ++i) {
        runoffT[base + i] = run;
        run += cntAT[base + i];
    }
}

// ---------------- CSR 3/4: scatter edges into bucket-grouped arrays ----------------
__global__ __launch_bounds__(256)
void scatterA_kernel(const int* __restrict__ src, const int* __restrict__ dst,
                     const int* __restrict__ runoffT,
                     int* __restrict__ srcb, int* __restrict__ dstb) {
    __shared__ int cur[NBUCK];
    const int tid = threadIdx.x, blk = blockIdx.x;
    if (tid < NBUCK) cur[tid] = runoffT[tid * NBLKA + blk];
    __syncthreads();
    const int e0 = blk * EPB;
    for (int i = tid; i < EPB; i += 256) {
        int s = src[e0 + i], d = dst[e0 + i];
        int pos = atomicAdd(&cur[d >> 7], 1);
        srcb[pos] = s;
        dstb[pos] = d;
    }
}

// ---------------- CSR 4/4: per-bucket node grouping; off/invdeg/sorted_src --------
__global__ __launch_bounds__(256)
void binB_kernel(const int* __restrict__ srcb, const int* __restrict__ dstb,
                 const int* __restrict__ runoffT, int* __restrict__ off,
                 float* __restrict__ invdeg, int* __restrict__ sorted_src) {
    __shared__ int cnt[NPB];
    __shared__ int curs[NPB];
    const int tid = threadIdx.x, b = blockIdx.x;
    const int base = runoffT[b * NBLKA];
    const int end  = (b == NBUCK - 1) ? N_EDGES : runoffT[(b + 1) * NBLKA];
    if (tid < NPB) cnt[tid] = 0;
    __syncthreads();
    for (int e = base + tid; e < end; e += 256) atomicAdd(&cnt[dstb[e] & (NPB - 1)], 1);
    __syncthreads();
    if (tid < 64) {   // wave-0 shfl scan of 128 counts (2 per lane)
        int c0 = cnt[tid * 2], c1 = cnt[tid * 2 + 1];
        int s = c0 + c1;
        int incl = s;
#pragma unroll
        for (int d = 1; d < 64; d <<= 1) {
            int u = __shfl_up(incl, d);
            if (tid >= d) incl += u;
        }
        int run = incl - s;
        curs[tid * 2] = run;
        curs[tid * 2 + 1] = run + c0;
    }
    __syncthreads();
    if (tid < NPB) {
        int n = b * NPB + tid;
        off[n] = base + curs[tid];
        if (n < N_NODES) invdeg[n] = 1.0f / fmaxf((float)cnt[tid], 1.0f);
        if (n == NPAD - 1) off[NPAD] = N_EDGES;
    }
    __syncthreads();
    for (int e = base + tid; e < end; e += 256) {
        int n = dstb[e] & (NPB - 1);
        int pos = base + atomicAdd(&curs[n], 1);
        sorted_src[pos] = srcb[e];
    }
}

// ---------------- prep: x f32->bf16 (blocks 0..1249) + 4x weight transpose ----------
__global__ __launch_bounds__(256)
void prep_kernel(const float* __restrict__ x, unsigned short* __restrict__ xb,
                 const float* __restrict__ w1s, const float* __restrict__ w1n,
                 const float* __restrict__ w2s, const float* __restrict__ w2n,
                 unsigned short* __restrict__ o1s, unsigned short* __restrict__ o1n,
                 unsigned short* __restrict__ o2s, unsigned short* __restrict__ o2n) {
    const int tid = threadIdx.x, blk = blockIdx.x;
    if (blk < 1250) {                      // cvt: 320000 float4 groups
        int i = blk * 256 + tid;
        float4 v = ((const float4*)x)[i];
        ushort4 o;
        o.x = f2bf(v.x); o.y = f2bf(v.y); o.z = f2bf(v.z); o.w = f2bf(v.w);
        ((ushort4*)xb)[i] = o;
    } else {                               // wtrans: 4 weights x 128 blocks
        int which = (blk - 1250) >> 7;
        const float* w = (which == 0) ? w1s : (which == 1) ? w1n : (which == 2) ? w2s : w2n;
        unsigned short* o = (which == 0) ? o1s : (which == 1) ? o1n : (which == 2) ? o2s : o2n;
        int K = (which < 2) ? DIM_IN : DIM_HID;
        int N = (which < 2) ? DIM_HID : DIM_OUT;
        int idx = ((blk - 1250) & 127) * 256 + tid;
        int n = idx / K, k = idx - n * K;
        o[n * K + k] = f2bf(w[k * N + n]);
    }
}

// ---------------- pull aggregation (R7-proven v1.5): 64 thr/node, 2 feat/lane -------
__global__ __launch_bounds__(64)
void agg_kernel(const unsigned short* __restrict__ feat, const int* __restrict__ sorted_src,
                const int* __restrict__ off, const float* __restrict__ invdeg,
                unsigned short* __restrict__ outa) {
    const int n = blockIdx.x;
    const int lane = threadIdx.x;
    const int s0 = off[n], s1 = off[n + 1];
    __shared__ int sidx[64];
    float a0 = 0.f, b0 = 0.f, a1 = 0.f, b1 = 0.f;
    float a2 = 0.f, b2 = 0.f, a3 = 0.f, b3 = 0.f;
    for (int base = s0; base < s1; base += 64) {
        sidx[lane] = sorted_src[min(base + lane, s1 - 1)];
        __syncthreads();
        int c = min(64, s1 - base);
        int i = 0;
        for (; i + 4 <= c; i += 4) {
            unsigned int u0 = *(const unsigned int*)&feat[(size_t)sidx[i + 0] * 128 + 2 * lane];
            unsigned int u1 = *(const unsigned int*)&feat[(size_t)sidx[i + 1] * 128 + 2 * lane];
            unsigned int u2 = *(const unsigned int*)&feat[(size_t)sidx[i + 2] * 128 + 2 * lane];
            unsigned int u3 = *(const unsigned int*)&feat[(size_t)sidx[i + 3] * 128 + 2 * lane];
            a0 += bflo(u0); b0 += bfhi(u0);
            a1 += bflo(u1); b1 += bfhi(u1);
            a2 += bflo(u2); b2 += bfhi(u2);
            a3 += bflo(u3); b3 += bfhi(u3);
        }
        for (; i < c; ++i) {
            unsigned int u = *(const unsigned int*)&feat[(size_t)sidx[i] * 128 + 2 * lane];
            a0 += bflo(u); b0 += bfhi(u);
        }
        __syncthreads();
    }
    float inv = invdeg[n];
    float slo = ((a0 + a1) + (a2 + a3)) * inv;
    float shi = ((b0 + b1) + (b2 + b3)) * inv;
    unsigned int packed = (unsigned int)f2bf(slo) | ((unsigned int)f2bf(shi) << 16);
    *(unsigned int*)&outa[(size_t)n * 128 + 2 * lane] = packed;
}

// ---------------- MFMA bf16 GEMM (R7-proven; layouts m89/m91-verified) ----------------
// C[M,N] = A1@B1T^T (+ A2@B2T^T) (+ bias) (relu?); BT is [N][K] bf16.
template<int PASSES, bool RELU, bool OUT_BF16>
__launch_bounds__(256)
__global__ void mfma_gemm(const unsigned short* __restrict__ A1, const unsigned short* __restrict__ B1T,
                          const unsigned short* __restrict__ A2, const unsigned short* __restrict__ B2T,
                          const float* __restrict__ bias,
                          void* __restrict__ Cout, int M, int N, int K) {
    const int tid = threadIdx.x;
    const int w = tid >> 6, lane = tid & 63;
    const int m0 = blockIdx.x * 64, n0 = blockIdx.y * 64;
    const int l15 = lane & 15;
    const int koff = (lane >> 4) * 8;
    const int rowc = min(m0 + w * 16 + l15, M - 1);

    f32x4 acc[4] = {};
#pragma unroll
    for (int pass = 0; pass < PASSES; ++pass) {
        const unsigned short* __restrict__ A  = (PASSES == 2 && pass) ? A2 : A1;
        const unsigned short* __restrict__ BT = (PASSES == 2 && pass) ? B2T : B1T;
        const unsigned short* arow = A + (size_t)rowc * K;
        for (int k0 = 0; k0 < K; k0 += 32) {
            bf16x8 af = *(const bf16x8*)(arow + k0 + koff);
#pragma unroll
            for (int f = 0; f < 4; ++f) {
                const unsigned short* brow = BT + (size_t)(n0 + f * 16 + l15) * K;
                bf16x8 bfr = *(const bf16x8*)(brow + k0 + koff);
                acc[f] = __builtin_amdgcn_mfma_f32_16x16x32_bf16(af, bfr, acc[f], 0, 0, 0);
            }
        }
    }

#pragma unroll
    for (int f = 0; f < 4; ++f) {
        int col = n0 + f * 16 + l15;
        float bv = bias ? bias[col] : 0.f;
#pragma unroll
        for (int r = 0; r < 4; ++r) {
            int grow = m0 + w * 16 + (lane >> 4) * 4 + r;
            if (grow < M) {
                float v = acc[f][r] + bv;
                if (RELU) v = fmaxf(v, 0.f);
                if (OUT_BF16) ((unsigned short*)Cout)[(size_t)grow * N + col] = f2bf(v);
                else          ((float*)Cout)[(size_t)grow * N + col] = v;
            }
        }
    }
}

// ---------------- gemm23: one pass over h -> t (bf16) AND outbase (f32) ----------------
// t = h@Wn2 (rounded to bf16, bit-identical to prior gemm2: f2bf(acc+0) == f2bf(acc));
// outbase = h@Ws2 raw f32 (bias/epi added later in aggadd).
__launch_bounds__(256)
__global__ void gemm23_kernel(const unsigned short* __restrict__ A,
                              const unsigned short* __restrict__ BnT,
                              const unsigned short* __restrict__ BsT,
                              unsigned short* __restrict__ t, float* __restrict__ outbase,
                              int M, int N, int K) {
    const int tid = threadIdx.x;
    const int w = tid >> 6, lane = tid & 63;
    const int m0 = blockIdx.x * 64, n0 = blockIdx.y * 64;
    const int l15 = lane & 15;
    const int koff = (lane >> 4) * 8;
    const int rowc = min(m0 + w * 16 + l15, M - 1);

    f32x4 accn[4] = {};
    f32x4 accs[4] = {};
    const unsigned short* arow = A + (size_t)rowc * K;
    for (int k0 = 0; k0 < K; k0 += 32) {
        bf16x8 af = *(const bf16x8*)(arow + k0 + koff);
#pragma unroll
        for (int f = 0; f < 4; ++f) {
            const unsigned short* bnrow = BnT + (size_t)(n0 + f * 16 + l15) * K;
            const unsigned short* bsrow = BsT + (size_t)(n0 + f * 16 + l15) * K;
            bf16x8 bn = *(const bf16x8*)(bnrow + k0 + koff);
            bf16x8 bs = *(const bf16x8*)(bsrow + k0 + koff);
            accn[f] = __builtin_amdgcn_mfma_f32_16x16x32_bf16(af, bn, accn[f], 0, 0, 0);
            accs[f] = __builtin_amdgcn_mfma_f32_16x16x32_bf16(af, bs, accs[f], 0, 0, 0);
        }
    }

#pragma unroll
    for (int f = 0; f < 4; ++f) {
        int col = n0 + f * 16 + l15;
#pragma unroll
        for (int r = 0; r < 4; ++r) {
            int grow = m0 + w * 16 + (lane >> 4) * 4 + r;
            if (grow < M) {
                t[(size_t)grow * N + col]       = f2bf(accn[f][r]);
                outbase[(size_t)grow * N + col] = accs[f][r];
            }
        }
    }
}

// ---------------- aggadd: out[n] = (outbase[n] + b2) + invdeg[n]*sum t[src] ---------
// Edge loop is the R7/R11-proven v1.5 pattern verbatim (same summation order).
__global__ __launch_bounds__(64)
void aggadd_kernel(const unsigned short* __restrict__ t, const int* __restrict__ sorted_src,
                   const int* __restrict__ off, const float* __restrict__ invdeg,
                   const float* __restrict__ outbase, const float* __restrict__ bias,
                   float* __restrict__ out) {
    const int n = blockIdx.x;
    const int lane = threadIdx.x;
    const int s0 = off[n], s1 = off[n + 1];
    __shared__ int sidx[64];
    float a0 = 0.f, b0 = 0.f, a1 = 0.f, b1 = 0.f;
    float a2 = 0.f, b2v = 0.f, a3 = 0.f, b3 = 0.f;
    for (int base = s0; base < s1; base += 64) {
        sidx[lane] = sorted_src[min(base + lane, s1 - 1)];
        __syncthreads();
        int c = min(64, s1 - base);
        int i = 0;
        for (; i + 4 <= c; i += 4) {
            unsigned int u0 = *(const unsigned int*)&t[(size_t)sidx[i + 0] * 128 + 2 * lane];
            unsigned int u1 = *(const unsigned int*)&t[(size_t)sidx[i + 1] * 128 + 2 * lane];
            unsigned int u2 = *(const unsigned int*)&t[(size_t)sidx[i + 2] * 128 + 2 * lane];
            unsigned int u3 = *(const unsigned int*)&t[(size_t)sidx[i + 3] * 128 + 2 * lane];
            a0 += bflo(u0); b0 += bfhi(u0);
            a1 += bflo(u1); b1 += bfhi(u1);
            a2 += bflo(u2); b2v += bfhi(u2);
            a3 += bflo(u3); b3 += bfhi(u3);
        }
        for (; i < c; ++i) {
            unsigned int u = *(const unsigned int*)&t[(size_t)sidx[i] * 128 + 2 * lane];
            a0 += bflo(u); b0 += bfhi(u);
        }
        __syncthreads();
    }
    float inv = invdeg[n];
    float slo = ((a0 + a1) + (a2 + a3)) * inv;
    float shi = ((b0 + b1) + (b2v + b3)) * inv;
    float2 ob = *(const float2*)&outbase[(size_t)n * 128 + 2 * lane];
    float2 o;
    o.x = (ob.x + bias[2 * lane])     + slo;
    o.y = (ob.y + bias[2 * lane + 1]) + shi;
    *(float2*)&out[(size_t)n * 128 + 2 * lane] = o;
}

extern "C" void kernel_launch(void* const* d_in, const int* in_sizes, int n_in,
                              void* d_out, int out_size, void* d_ws, size_t ws_size,
                              hipStream_t stream) {
    const float* x        = (const float*)d_in[0];
    const float* w_self1  = (const float*)d_in[1];
    const float* w_neigh1 = (const float*)d_in[2];
    const float* b1       = (const float*)d_in[3];
    const float* w_self2  = (const float*)d_in[4];
    const float* w_neigh2 = (const float*)d_in[5];
    const float* b2       = (const float*)d_in[6];
    const int*   src      = (const int*)d_in[7];
    const int*   dst      = (const int*)d_in[8];
    float* out = (float*)d_out;

    // workspace layout, 1 KiB-aligned regions
    char* p = (char*)d_ws;
    auto alloc = [&](size_t bytes) { char* q = p; p += (bytes + 1023) & ~(size_t)1023; return q; };
    int*            cntAT      = (int*)alloc(NBUCK * NBLKA * 4);
    int*            runoffT    = (int*)alloc(NBUCK * NBLKA * 4);
    int*            srcb       = (int*)alloc((size_t)N_EDGES * 4);
    int*            dstb       = (int*)alloc((size_t)N_EDGES * 4);
    int*            off        = (int*)alloc((NPAD + 1) * 4);
    int*            sorted_src = (int*)alloc((size_t)N_EDGES * 4);
    float*          invdeg     = (float*)alloc(NPAD * 4);
    unsigned short* xb         = (unsigned short*)alloc((size_t)N_NODES * DIM_IN * 2);
    unsigned short* w1sT       = (unsigned short*)alloc(DIM_IN * DIM_HID * 2);
    unsigned short* w1nT       = (unsigned short*)alloc(DIM_IN * DIM_HID * 2);
    unsigned short* w2sT       = (unsigned short*)alloc(DIM_HID * DIM_OUT * 2);
    unsigned short* w2nT       = (unsigned short*)alloc(DIM_HID * DIM_OUT * 2);
    unsigned short* aggbuf     = (unsigned short*)alloc((size_t)N_NODES * 128 * 2);
    unsigned short* h          = (unsigned short*)alloc((size_t)N_NODES * DIM_HID * 2);
    unsigned short* t          = (unsigned short*)alloc((size_t)N_NODES * DIM_OUT * 2);
    float*          outbase    = (float*)alloc((size_t)N_NODES * DIM_OUT * 4);

    // ---- CSR build (atomic-free, exclusive-ownership) ----
    countA_kernel  <<<NBLKA, 256, 0, stream>>>(dst, cntAT);
    scanB_kernel   <<<1, 64, 0, stream>>>(cntAT, runoffT);
    scatterA_kernel<<<NBLKA, 256, 0, stream>>>(src, dst, runoffT, srcb, dstb);
    binB_kernel    <<<NBUCK, 256, 0, stream>>>(srcb, dstb, runoffT, off, invdeg, sorted_src);

    // ---- dtype prep (cvt + 4 weight transposes, one kernel) ----
    prep_kernel<<<1250 + 512, 256, 0, stream>>>(x, xb, w_self1, w_neigh1, w_self2, w_neigh2,
                                                w1sT, w1nT, w2sT, w2nT);

    // ---- layer 1: h = relu(x@Ws1 + agg(x)@Wn1 + b1) ----
    agg_kernel<<<N_NODES, 64, 0, stream>>>(xb, sorted_src, off, invdeg, aggbuf);
    mfma_gemm<2, true, true><<<dim3(157, DIM_HID / 64), 256, 0, stream>>>(
        xb, w1sT, aggbuf, w1nT, b1, h, N_NODES, DIM_HID, DIM_IN);

    // ---- layer 2: {t, outbase} = h@{Wn2, Ws2} one pass; out = (outbase+b2)+agg(t) ----
    gemm23_kernel<<<dim3(157, DIM_OUT / 64), 256, 0, stream>>>(
        h, w2nT, w2sT, t, outbase, N_NODES, DIM_OUT, DIM_HID);
    aggadd_kernel<<<N_NODES, 64, 0, stream>>>(t, sorted_src, off, invdeg, outbase, b2, out);
}

// Round 15
// 185.074 us; speedup vs baseline: 12.6770x; 1.0499x over previous
//
#include <hip/hip_runtime.h>

#define N_NODES 10000
#define N_EDGES 640000
#define DIM_IN  128
#define DIM_HID 256
#define DIM_OUT 128
#define NPAD    10240   // NBUCK * NPB
#define NBUCK   80      // buckets; bucket = dst >> 7
#define NPB     128     // nodes per bucket
#define NBLKA   160     // edge-partition blocks
#define EPB     4000    // edges per block; NBLKA*EPB == N_EDGES

typedef __attribute__((ext_vector_type(8))) short bf16x8;
typedef __attribute__((ext_vector_type(4))) float f32x4;

__device__ __forceinline__ unsigned short f2bf(float f) {
    unsigned int u = __float_as_uint(f);
    return (unsigned short)((u + 0x7fffu + ((u >> 16) & 1u)) >> 16);   // RNE
}
__device__ __forceinline__ float bf2f(unsigned short h) {
    return __uint_as_float(((unsigned int)h) << 16);
}
__device__ __forceinline__ float bflo(unsigned int u) { return __uint_as_float(u << 16); }
__device__ __forceinline__ float bfhi(unsigned int u) { return __uint_as_float(u & 0xffff0000u); }

// ---------------- CSR 1/4: per-(block,bucket) counts, LDS histogram ----------------
__global__ __launch_bounds__(256)
void countA_kernel(const int* __restrict__ dst, int* __restrict__ cntAT) {
    __shared__ int c[NBUCK];
    const int tid = threadIdx.x, blk = blockIdx.x;
    if (tid < NBUCK) c[tid] = 0;
    __syncthreads();
    const int e0 = blk * EPB;
    for (int i = tid; i < EPB; i += 256) atomicAdd(&c[dst[e0 + i] >> 7], 1);
    __syncthreads();
    if (tid < NBUCK) cntAT[tid * NBLKA + blk] = c[tid];   // transposed: bucket-major
}

// ---------------- CSR 2/4: single-wave scan of 12800 run counts ----------------
__global__ __launch_bounds__(64)
void scanB_kernel(const int* __restrict__ cntAT, int* __restrict__ runoffT) {
    const int lane = threadIdx.x;
    const int base = lane * (NBUCK * NBLKA / 64);     // 200 per lane
    int s = 0;
    for (int i = 0; i < NBUCK * NBLKA / 64; ++i) s += cntAT[base + i];
    int incl = s;
#pragma unroll
    for (int d = 1; d < 64; d <<= 1) {
        int u = __shfl_up(incl, d);
        if (lane >= d) incl += u;
    }
    int run = incl - s;
    for (int i = 0; i < NBUCK * NBLKA / 64; ++i) {
        runoffT[base + i] = run;
        run += cntAT[base + i];
    }
}

// ---------------- CSR 3/4: scatter PACKED edges into bucket-grouped array ----------
// payload = (src << 7) | (dst & 127): src fits 14 bits, node-in-bucket 7 bits.
__global__ __launch_bounds__(256)
void scatterA_kernel(const int* __restrict__ src, const int* __restrict__ dst,
                     const int* __restrict__ runoffT, int* __restrict__ edges) {
    __shared__ int cur[NBUCK];
    const int tid = threadIdx.x, blk = blockIdx.x;
    if (tid < NBUCK) cur[tid] = runoffT[tid * NBLKA + blk];
    __syncthreads();
    const int e0 = blk * EPB;
    for (int i = tid; i < EPB; i += 256) {
        int s = src[e0 + i], d = dst[e0 + i];
        int pos = atomicAdd(&cur[d >> 7], 1);
        edges[pos] = (s << 7) | (d & (NPB - 1));
    }
}

// ---------------- CSR 4/4: per-bucket node grouping; off/invdeg/sorted_src --------
__global__ __launch_bounds__(256)
void binB_kernel(const int* __restrict__ edges, const int* __restrict__ runoffT,
                 int* __restrict__ off, float* __restrict__ invdeg,
                 int* __restrict__ sorted_src) {
    __shared__ int cnt[NPB];
    __shared__ int curs[NPB];
    const int tid = threadIdx.x, b = blockIdx.x;
    const int base = runoffT[b * NBLKA];
    const int end  = (b == NBUCK - 1) ? N_EDGES : runoffT[(b + 1) * NBLKA];
    if (tid < NPB) cnt[tid] = 0;
    __syncthreads();
    for (int e = base + tid; e < end; e += 256) atomicAdd(&cnt[edges[e] & (NPB - 1)], 1);
    __syncthreads();
    if (tid < 64) {   // wave-0 shfl scan of 128 counts (2 per lane)
        int c0 = cnt[tid * 2], c1 = cnt[tid * 2 + 1];
        int s = c0 + c1;
        int incl = s;
#pragma unroll
        for (int d = 1; d < 64; d <<= 1) {
            int u = __shfl_up(incl, d);
            if (tid >= d) incl += u;
        }
        int run = incl - s;
        curs[tid * 2] = run;
        curs[tid * 2 + 1] = run + c0;
    }
    __syncthreads();
    if (tid < NPB) {
        int n = b * NPB + tid;
        off[n] = base + curs[tid];
        if (n < N_NODES) invdeg[n] = 1.0f / fmaxf((float)cnt[tid], 1.0f);
        if (n == NPAD - 1) off[NPAD] = N_EDGES;
    }
    __syncthreads();
    for (int e = base + tid; e < end; e += 256) {
        int v = edges[e];
        int n = v & (NPB - 1);
        int pos = base + atomicAdd(&curs[n], 1);
        sorted_src[pos] = v >> 7;
    }
}

// ---------------- prep: x f32->bf16 (blocks 0..1249) + 4x weight transpose ----------
__global__ __launch_bounds__(256)
void prep_kernel(const float* __restrict__ x, unsigned short* __restrict__ xb,
                 const float* __restrict__ w1s, const float* __restrict__ w1n,
                 const float* __restrict__ w2s, const float* __restrict__ w2n,
                 unsigned short* __restrict__ o1s, unsigned short* __restrict__ o1n,
                 unsigned short* __restrict__ o2s, unsigned short* __restrict__ o2n) {
    const int tid = threadIdx.x, blk = blockIdx.x;
    if (blk < 1250) {                      // cvt: 320000 float4 groups
        int i = blk * 256 + tid;
        float4 v = ((const float4*)x)[i];
        ushort4 o;
        o.x = f2bf(v.x); o.y = f2bf(v.y); o.z = f2bf(v.z); o.w = f2bf(v.w);
        ((ushort4*)xb)[i] = o;
    } else {                               // wtrans: 4 weights x 128 blocks
        int which = (blk - 1250) >> 7;
        const float* w = (which == 0) ? w1s : (which == 1) ? w1n : (which == 2) ? w2s : w2n;
        unsigned short* o = (which == 0) ? o1s : (which == 1) ? o1n : (which == 2) ? o2s : o2n;
        int K = (which < 2) ? DIM_IN : DIM_HID;
        int N = (which < 2) ? DIM_HID : DIM_OUT;
        int idx = ((blk - 1250) & 127) * 256 + tid;
        int n = idx / K, k = idx - n * K;
        o[n * K + k] = f2bf(w[k * N + n]);
    }
}

// ---------------- pull aggregation (R12-proven v1.5): 64 thr/node, 2 feat/lane ------
__global__ __launch_bounds__(64)
void agg_kernel(const unsigned short* __restrict__ feat, const int* __restrict__ sorted_src,
                const int* __restrict__ off, const float* __restrict__ invdeg,
                unsigned short* __restrict__ outa) {
    const int n = blockIdx.x;
    const int lane = threadIdx.x;
    const int s0 = off[n], s1 = off[n + 1];
    __shared__ int sidx[64];
    float a0 = 0.f, b0 = 0.f, a1 = 0.f, b1 = 0.f;
    float a2 = 0.f, b2 = 0.f, a3 = 0.f, b3 = 0.f;
    for (int base = s0; base < s1; base += 64) {
        sidx[lane] = sorted_src[min(base + lane, s1 - 1)];
        __syncthreads();
        int c = min(64, s1 - base);
        int i = 0;
        for (; i + 4 <= c; i += 4) {
            unsigned int u0 = *(const unsigned int*)&feat[(size_t)sidx[i + 0] * 128 + 2 * lane];
            unsigned int u1 = *(const unsigned int*)&feat[(size_t)sidx[i + 1] * 128 + 2 * lane];
            unsigned int u2 = *(const unsigned int*)&feat[(size_t)sidx[i + 2] * 128 + 2 * lane];
            unsigned int u3 = *(const unsigned int*)&feat[(size_t)sidx[i + 3] * 128 + 2 * lane];
            a0 += bflo(u0); b0 += bfhi(u0);
            a1 += bflo(u1); b1 += bfhi(u1);
            a2 += bflo(u2); b2 += bfhi(u2);
            a3 += bflo(u3); b3 += bfhi(u3);
        }
        for (; i < c; ++i) {
            unsigned int u = *(const unsigned int*)&feat[(size_t)sidx[i] * 128 + 2 * lane];
            a0 += bflo(u); b0 += bfhi(u);
        }
        __syncthreads();
    }
    float inv = invdeg[n];
    float slo = ((a0 + a1) + (a2 + a3)) * inv;
    float shi = ((b0 + b1) + (b2 + b3)) * inv;
    unsigned int packed = (unsigned int)f2bf(slo) | ((unsigned int)f2bf(shi) << 16);
    *(unsigned int*)&outa[(size_t)n * 128 + 2 * lane] = packed;
}

// ---------------- MFMA bf16 GEMM (R7-proven; layouts m89/m91-verified) ----------------
// C[M,N] = A1@B1T^T (+ A2@B2T^T) (+ bias) (relu?); BT is [N][K] bf16.
template<int PASSES, bool RELU, bool OUT_BF16>
__launch_bounds__(256)
__global__ void mfma_gemm(const unsigned short* __restrict__ A1, const unsigned short* __restrict__ B1T,
                          const unsigned short* __restrict__ A2, const unsigned short* __restrict__ B2T,
                          const float* __restrict__ bias,
                          void* __restrict__ Cout, int M, int N, int K) {
    const int tid = threadIdx.x;
    const int w = tid >> 6, lane = tid & 63;
    const int m0 = blockIdx.x * 64, n0 = blockIdx.y * 64;
    const int l15 = lane & 15;
    const int koff = (lane >> 4) * 8;
    const int rowc = min(m0 + w * 16 + l15, M - 1);

    f32x4 acc[4] = {};
#pragma unroll
    for (int pass = 0; pass < PASSES; ++pass) {
        const unsigned short* __restrict__ A  = (PASSES == 2 && pass) ? A2 : A1;
        const unsigned short* __restrict__ BT = (PASSES == 2 && pass) ? B2T : B1T;
        const unsigned short* arow = A + (size_t)rowc * K;
        for (int k0 = 0; k0 < K; k0 += 32) {
            bf16x8 af = *(const bf16x8*)(arow + k0 + koff);
#pragma unroll
            for (int f = 0; f < 4; ++f) {
                const unsigned short* brow = BT + (size_t)(n0 + f * 16 + l15) * K;
                bf16x8 bfr = *(const bf16x8*)(brow + k0 + koff);
                acc[f] = __builtin_amdgcn_mfma_f32_16x16x32_bf16(af, bfr, acc[f], 0, 0, 0);
            }
        }
    }

#pragma unroll
    for (int f = 0; f < 4; ++f) {
        int col = n0 + f * 16 + l15;
        float bv = bias ? bias[col] : 0.f;
#pragma unroll
        for (int r = 0; r < 4; ++r) {
            int grow = m0 + w * 16 + (lane >> 4) * 4 + r;
            if (grow < M) {
                float v = acc[f][r] + bv;
                if (RELU) v = fmaxf(v, 0.f);
                if (OUT_BF16) ((unsigned short*)Cout)[(size_t)grow * N + col] = f2bf(v);
                else          ((float*)Cout)[(size_t)grow * N + col] = v;
            }
        }
    }
}

// ---------------- gemm23: one pass over h -> t (bf16) AND outbase (f32) ----------------
__launch_bounds__(256)
__global__ void gemm23_kernel(const unsigned short* __restrict__ A,
                              const unsigned short* __restrict__ BnT,
                              const unsigned short* __restrict__ BsT,
                              unsigned short* __restrict__ t, float* __restrict__ outbase,
                              int M, int N, int K) {
    const int tid = threadIdx.x;
    const int w = tid >> 6, lane = tid & 63;
    const int m0 = blockIdx.x * 64, n0 = blockIdx.y * 64;
    const int l15 = lane & 15;
    const int koff = (lane >> 4) * 8;
    const int rowc = min(m0 + w * 16 + l15, M - 1);

    f32x4 accn[4] = {};
    f32x4 accs[4] = {};
    const unsigned short* arow = A + (size_t)rowc * K;
    for (int k0 = 0; k0 < K; k0 += 32) {
        bf16x8 af = *(const bf16x8*)(arow + k0 + koff);
#pragma unroll
        for (int f = 0; f < 4; ++f) {
            const unsigned short* bnrow = BnT + (size_t)(n0 + f * 16 + l15) * K;
            const unsigned short* bsrow = BsT + (size_t)(n0 + f * 16 + l15) * K;
            bf16x8 bn = *(const bf16x8*)(bnrow + k0 + koff);
            bf16x8 bs = *(const bf16x8*)(bsrow + k0 + koff);
            accn[f] = __builtin_amdgcn_mfma_f32_16x16x32_bf16(af, bn, accn[f], 0, 0, 0);
            accs[f] = __builtin_amdgcn_mfma_f32_16x16x32_bf16(af, bs, accs[f], 0, 0, 0);
        }
    }

#pragma unroll
    for (int f = 0; f < 4; ++f) {
        int col = n0 + f * 16 + l15;
#pragma unroll
        for (int r = 0; r < 4; ++r) {
            int grow = m0 + w * 16 + (lane >> 4) * 4 + r;
            if (grow < M) {
                t[(size_t)grow * N + col]       = f2bf(accn[f][r]);
                outbase[(size_t)grow * N + col] = accs[f][r];
            }
        }
    }
}

// ---------------- aggadd (R12-proven v1.5 loop): out = (outbase+b2) + invdeg*sum t ----
__global__ __launch_bounds__(64)
void aggadd_kernel(const unsigned short* __restrict__ t, const int* __restrict__ sorted_src,
                   const int* __restrict__ off, const float* __restrict__ invdeg,
                   const float* __restrict__ outbase, const float* __restrict__ bias,
                   float* __restrict__ out) {
    const int n = blockIdx.x;
    const int lane = threadIdx.x;
    const int s0 = off[n], s1 = off[n + 1];
    __shared__ int sidx[64];
    float a0 = 0.f, b0 = 0.f, a1 = 0.f, b1 = 0.f;
    float a2 = 0.f, b2v = 0.f, a3 = 0.f, b3 = 0.f;
    for (int base = s0; base < s1; base += 64) {
        sidx[lane] = sorted_src[min(base + lane, s1 - 1)];
        __syncthreads();
        int c = min(64, s1 - base);
        int i = 0;
        for (; i + 4 <= c; i += 4) {
            unsigned int u0 = *(const unsigned int*)&t[(size_t)sidx[i + 0] * 128 + 2 * lane];
            unsigned int u1 = *(const unsigned int*)&t[(size_t)sidx[i + 1] * 128 + 2 * lane];
            unsigned int u2 = *(const unsigned int*)&t[(size_t)sidx[i + 2] * 128 + 2 * lane];
            unsigned int u3 = *(const unsigned int*)&t[(size_t)sidx[i + 3] * 128 + 2 * lane];
            a0 += bflo(u0); b0 += bfhi(u0);
            a1 += bflo(u1); b1 += bfhi(u1);
            a2 += bflo(u2); b2v += bfhi(u2);
            a3 += bflo(u3); b3 += bfhi(u3);
        }
        for (; i < c; ++i) {
            unsigned int u = *(const unsigned int*)&t[(size_t)sidx[i] * 128 + 2 * lane];
            a0 += bflo(u); b0 += bfhi(u);
        }
        __syncthreads();
    }
    float inv = invdeg[n];
    float slo = ((a0 + a1) + (a2 + a3)) * inv;
    float shi = ((b0 + b1) + (b2v + b3)) * inv;
    float2 ob = *(const float2*)&outbase[(size_t)n * 128 + 2 * lane];
    float2 o;
    o.x = (ob.x + bias[2 * lane])     + slo;
    o.y = (ob.y + bias[2 * lane + 1]) + shi;
    *(float2*)&out[(size_t)n * 128 + 2 * lane] = o;
}

extern "C" void kernel_launch(void* const* d_in, const int* in_sizes, int n_in,
                              void* d_out, int out_size, void* d_ws, size_t ws_size,
                              hipStream_t stream) {
    const float* x        = (const float*)d_in[0];
    const float* w_self1  = (const float*)d_in[1];
    const float* w_neigh1 = (const float*)d_in[2];
    const float* b1       = (const float*)d_in[3];
    const float* w_self2  = (const float*)d_in[4];
    const float* w_neigh2 = (const float*)d_in[5];
    const float* b2       = (const float*)d_in[6];
    const int*   src      = (const int*)d_in[7];
    const int*   dst      = (const int*)d_in[8];
    float* out = (float*)d_out;

    // workspace layout, 1 KiB-aligned regions
    char* p = (char*)d_ws;
    auto alloc = [&](size_t bytes) { char* q = p; p += (bytes + 1023) & ~(size_t)1023; return q; };
    int*            cntAT      = (int*)alloc(NBUCK * NBLKA * 4);
    int*            runoffT    = (int*)alloc(NBUCK * NBLKA * 4);
    int*            edges      = (int*)alloc((size_t)N_EDGES * 4);   // packed (src<<7)|(dst&127)
    int*            off        = (int*)alloc((NPAD + 1) * 4);
    int*            sorted_src = (int*)alloc((size_t)N_EDGES * 4);
    float*          invdeg     = (float*)alloc(NPAD * 4);
    unsigned short* xb         = (unsigned short*)alloc((size_t)N_NODES * DIM_IN * 2);
    unsigned short* w1sT       = (unsigned short*)alloc(DIM_IN * DIM_HID * 2);
    unsigned short* w1nT       = (unsigned short*)alloc(DIM_IN * DIM_HID * 2);
    unsigned short* w2sT       = (unsigned short*)alloc(DIM_HID * DIM_OUT * 2);
    unsigned short* w2nT       = (unsigned short*)alloc(DIM_HID * DIM_OUT * 2);
    unsigned short* aggbuf     = (unsigned short*)alloc((size_t)N_NODES * 128 * 2);
    unsigned short* h          = (unsigned short*)alloc((size_t)N_NODES * DIM_HID * 2);
    unsigned short* t          = (unsigned short*)alloc((size_t)N_NODES * DIM_OUT * 2);
    float*          outbase    = (float*)alloc((size_t)N_NODES * DIM_OUT * 4);

    // ---- CSR build (atomic-free-global, exclusive-ownership, packed payload) ----
    countA_kernel  <<<NBLKA, 256, 0, stream>>>(dst, cntAT);
    scanB_kernel   <<<1, 64, 0, stream>>>(cntAT, runoffT);
    scatterA_kernel<<<NBLKA, 256, 0, stream>>>(src, dst, runoffT, edges);
    binB_kernel    <<<NBUCK, 256, 0, stream>>>(edges, runoffT, off, invdeg, sorted_src);

    // ---- dtype prep (cvt + 4 weight transposes, one kernel) ----
    prep_kernel<<<1250 + 512, 256, 0, stream>>>(x, xb, w_self1, w_neigh1, w_self2, w_neigh2,
                                                w1sT, w1nT, w2sT, w2nT);

    // ---- layer 1: h = relu(x@Ws1 + agg(x)@Wn1 + b1) ----
    agg_kernel<<<N_NODES, 64, 0, stream>>>(xb, sorted_src, off, invdeg, aggbuf);
    mfma_gemm<2, true, true><<<dim3(157, DIM_HID / 64), 256, 0, stream>>>(
        xb, w1sT, aggbuf, w1nT, b1, h, N_NODES, DIM_HID, DIM_IN);

    // ---- layer 2: {t, outbase} = h@{Wn2, Ws2} one pass; out = (outbase+b2)+agg(t) ----
    gemm23_kernel<<<dim3(157, DIM_OUT / 64), 256, 0, stream>>>(
        h, w2nT, w2sT, t, outbase, N_NODES, DIM_OUT, DIM_HID);
    aggadd_kernel<<<N_NODES, 64, 0, stream>>>(t, sorted_src, off, invdeg, outbase, b2, out);
}

// Round 16
// 181.950 us; speedup vs baseline: 12.8947x; 1.0172x over previous
//
#include <hip/hip_runtime.h>

#define N_NODES 10000
#define N_EDGES 640000
#define DIM_IN  128
#define DIM_HID 256
#define DIM_OUT 128
#define NPAD    10240   // NBUCK * NPB
#define NBUCK   80      // buckets; bucket = dst >> 7
#define NPB     128     // nodes per bucket
#define NBLKA   160     // edge-partition blocks
#define EPB     4000    // edges per block; NBLKA*EPB == N_EDGES

typedef __attribute__((ext_vector_type(8))) short bf16x8;
typedef __attribute__((ext_vector_type(4))) float f32x4;

__device__ __forceinline__ unsigned short f2bf(float f) {
    unsigned int u = __float_as_uint(f);
    return (unsigned short)((u + 0x7fffu + ((u >> 16) & 1u)) >> 16);   // RNE
}
__device__ __forceinline__ float bf2f(unsigned short h) {
    return __uint_as_float(((unsigned int)h) << 16);
}
__device__ __forceinline__ float bflo(unsigned int u) { return __uint_as_float(u << 16); }
__device__ __forceinline__ float bfhi(unsigned int u) { return __uint_as_float(u & 0xffff0000u); }

// ---------------- fused prep + countA ----------------
// blocks 0..1249: x f32->bf16; 1250..1761: weight transpose; 1762..1921: countA hist.
__global__ __launch_bounds__(256)
void prepc_kernel(const float* __restrict__ x, unsigned short* __restrict__ xb,
                  const float* __restrict__ w1s, const float* __restrict__ w1n,
                  const float* __restrict__ w2s, const float* __restrict__ w2n,
                  unsigned short* __restrict__ o1s, unsigned short* __restrict__ o1n,
                  unsigned short* __restrict__ o2s, unsigned short* __restrict__ o2n,
                  const int* __restrict__ dst, int* __restrict__ cntAT) {
    __shared__ int c[NBUCK];
    const int tid = threadIdx.x, blk = blockIdx.x;
    if (blk < 1250) {                      // cvt: 320000 float4 groups
        int i = blk * 256 + tid;
        float4 v = ((const float4*)x)[i];
        ushort4 o;
        o.x = f2bf(v.x); o.y = f2bf(v.y); o.z = f2bf(v.z); o.w = f2bf(v.w);
        ((ushort4*)xb)[i] = o;
    } else if (blk < 1762) {               // wtrans: 4 weights x 128 blocks
        int which = (blk - 1250) >> 7;
        const float* w = (which == 0) ? w1s : (which == 1) ? w1n : (which == 2) ? w2s : w2n;
        unsigned short* o = (which == 0) ? o1s : (which == 1) ? o1n : (which == 2) ? o2s : o2n;
        int K = (which < 2) ? DIM_IN : DIM_HID;
        int N = (which < 2) ? DIM_HID : DIM_OUT;
        int idx = ((blk - 1250) & 127) * 256 + tid;
        int n = idx / K, k = idx - n * K;
        o[n * K + k] = f2bf(w[k * N + n]);
    } else {                               // countA: 160 blocks, LDS histogram
        int ablk = blk - 1762;
        if (tid < NBUCK) c[tid] = 0;
        __syncthreads();
        const int e0 = ablk * EPB;
        for (int i = tid; i < EPB; i += 256) atomicAdd(&c[dst[e0 + i] >> 7], 1);
        __syncthreads();
        if (tid < NBUCK) cntAT[tid * NBLKA + ablk] = c[tid];
    }
}

// ---------------- CSR 2/4: single-wave scan of 12800 run counts ----------------
__global__ __launch_bounds__(64)
void scanB_kernel(const int* __restrict__ cntAT, int* __restrict__ runoffT) {
    const int lane = threadIdx.x;
    const int base = lane * (NBUCK * NBLKA / 64);     // 200 per lane
    int s = 0;
    for (int i = 0; i < NBUCK * NBLKA / 64; ++i) s += cntAT[base + i];
    int incl = s;
#pragma unroll
    for (int d = 1; d < 64; d <<= 1) {
        int u = __shfl_up(incl, d);
        if (lane >= d) incl += u;
    }
    int run = incl - s;
    for (int i = 0; i < NBUCK * NBLKA / 64; ++i) {
        runoffT[base + i] = run;
        run += cntAT[base + i];
    }
}

// ---------------- CSR 3/4: scatter PACKED edges into bucket-grouped array ----------
// payload = (src << 7) | (dst & 127): src fits 14 bits, node-in-bucket 7 bits.
__global__ __launch_bounds__(256)
void scatterA_kernel(const int* __restrict__ src, const int* __restrict__ dst,
                     const int* __restrict__ runoffT, int* __restrict__ edges) {
    __shared__ int cur[NBUCK];
    const int tid = threadIdx.x, blk = blockIdx.x;
    if (tid < NBUCK) cur[tid] = runoffT[tid * NBLKA + blk];
    __syncthreads();
    const int e0 = blk * EPB;
    for (int i = tid; i < EPB; i += 256) {
        int s = src[e0 + i], d = dst[e0 + i];
        int pos = atomicAdd(&cur[d >> 7], 1);
        edges[pos] = (s << 7) | (d & (NPB - 1));
    }
}

// ---------------- CSR 4/4: per-bucket grouping, PER-WAVE private counters ----------
// Wave w owns a contiguous quarter of the bucket's edges and its own cnt/curs copy:
// no cross-wave LDS-atomic contention. Per-node output = 4 concatenated segments.
__global__ __launch_bounds__(256)
void binB_kernel(const int* __restrict__ edges, const int* __restrict__ runoffT,
                 int* __restrict__ off, float* __restrict__ invdeg,
                 int* __restrict__ sorted_src) {
    __shared__ int cnt[4][NPB];
    __shared__ int curs[4][NPB];
    const int tid = threadIdx.x, b = blockIdx.x;
    const int w = tid >> 6, lane = tid & 63;
    const int base = runoffT[b * NBLKA];
    const int end  = (b == NBUCK - 1) ? N_EDGES : runoffT[(b + 1) * NBLKA];
    const int len  = end - base;
    const int q0 = base + (len * w) / 4;
    const int q1 = base + (len * (w + 1)) / 4;
    cnt[w][lane] = 0; cnt[w][lane + 64] = 0;
    __syncthreads();
    for (int e = q0 + lane; e < q1; e += 64) atomicAdd(&cnt[w][edges[e] & (NPB - 1)], 1);
    __syncthreads();
    if (w == 0) {   // wave 0: totals, node scan, per-wave cursor bases (2 nodes/lane)
        int n0 = 2 * lane, n1 = 2 * lane + 1;
        int c00 = cnt[0][n0], c10 = cnt[1][n0], c20 = cnt[2][n0], c30 = cnt[3][n0];
        int c01 = cnt[0][n1], c11 = cnt[1][n1], c21 = cnt[2][n1], c31 = cnt[3][n1];
        int t0 = c00 + c10 + c20 + c30;
        int t1 = c01 + c11 + c21 + c31;
        int s = t0 + t1;
        int incl = s;
#pragma unroll
        for (int d = 1; d < 64; d <<= 1) {
            int u = __shfl_up(incl, d);
            if (lane >= d) incl += u;
        }
        int run = incl - s;                // exclusive prefix within bucket
        int g0 = b * NPB + n0, g1 = b * NPB + n1;
        off[g0] = base + run;
        off[g1] = base + run + t0;
        if (g0 < N_NODES) invdeg[g0] = 1.0f / fmaxf((float)t0, 1.0f);
        if (g1 < N_NODES) invdeg[g1] = 1.0f / fmaxf((float)t1, 1.0f);
        if (g1 == NPAD - 1) off[NPAD] = N_EDGES;
        curs[0][n0] = base + run;
        curs[1][n0] = base + run + c00;
        curs[2][n0] = base + run + c00 + c10;
        curs[3][n0] = base + run + c00 + c10 + c20;
        int r1 = run + t0;
        curs[0][n1] = base + r1;
        curs[1][n1] = base + r1 + c01;
        curs[2][n1] = base + r1 + c01 + c11;
        curs[3][n1] = base + r1 + c01 + c11 + c21;
    }
    __syncthreads();
    for (int e = q0 + lane; e < q1; e += 64) {
        int v = edges[e];
        int n = v & (NPB - 1);
        int pos = atomicAdd(&curs[w][n], 1);
        sorted_src[pos] = v >> 7;
    }
}

// ---------------- pull aggregation: v1.5 staging, 8 loads in flight ------------------
__global__ __launch_bounds__(64)
void agg_kernel(const unsigned short* __restrict__ feat, const int* __restrict__ sorted_src,
                const int* __restrict__ off, const float* __restrict__ invdeg,
                unsigned short* __restrict__ outa) {
    const int n = blockIdx.x;
    const int lane = threadIdx.x;
    const int s0 = off[n], s1 = off[n + 1];
    __shared__ int sidx[64];
    float a0 = 0.f, b0 = 0.f, a1 = 0.f, b1 = 0.f;
    float a2 = 0.f, b2 = 0.f, a3 = 0.f, b3 = 0.f;
    for (int base = s0; base < s1; base += 64) {
        sidx[lane] = sorted_src[min(base + lane, s1 - 1)];
        __syncthreads();
        int c = min(64, s1 - base);
        int i = 0;
        for (; i + 8 <= c; i += 8) {
            unsigned int u0 = *(const unsigned int*)&feat[(size_t)sidx[i + 0] * 128 + 2 * lane];
            unsigned int u1 = *(const unsigned int*)&feat[(size_t)sidx[i + 1] * 128 + 2 * lane];
            unsigned int u2 = *(const unsigned int*)&feat[(size_t)sidx[i + 2] * 128 + 2 * lane];
            unsigned int u3 = *(const unsigned int*)&feat[(size_t)sidx[i + 3] * 128 + 2 * lane];
            unsigned int u4 = *(const unsigned int*)&feat[(size_t)sidx[i + 4] * 128 + 2 * lane];
            unsigned int u5 = *(const unsigned int*)&feat[(size_t)sidx[i + 5] * 128 + 2 * lane];
            unsigned int u6 = *(const unsigned int*)&feat[(size_t)sidx[i + 6] * 128 + 2 * lane];
            unsigned int u7 = *(const unsigned int*)&feat[(size_t)sidx[i + 7] * 128 + 2 * lane];
            a0 += bflo(u0); b0 += bfhi(u0);
            a1 += bflo(u1); b1 += bfhi(u1);
            a2 += bflo(u2); b2 += bfhi(u2);
            a3 += bflo(u3); b3 += bfhi(u3);
            a0 += bflo(u4); b0 += bfhi(u4);
            a1 += bflo(u5); b1 += bfhi(u5);
            a2 += bflo(u6); b2 += bfhi(u6);
            a3 += bflo(u7); b3 += bfhi(u7);
        }
        for (; i < c; ++i) {
            unsigned int u = *(const unsigned int*)&feat[(size_t)sidx[i] * 128 + 2 * lane];
            a0 += bflo(u); b0 += bfhi(u);
        }
        __syncthreads();
    }
    float inv = invdeg[n];
    float slo = ((a0 + a1) + (a2 + a3)) * inv;
    float shi = ((b0 + b1) + (b2 + b3)) * inv;
    unsigned int packed = (unsigned int)f2bf(slo) | ((unsigned int)f2bf(shi) << 16);
    *(unsigned int*)&outa[(size_t)n * 128 + 2 * lane] = packed;
}

// ---------------- MFMA bf16 GEMM (R7-proven; layouts m89/m91-verified) ----------------
// C[M,N] = A1@B1T^T (+ A2@B2T^T) (+ bias) (relu?); BT is [N][K] bf16.
template<int PASSES, bool RELU, bool OUT_BF16>
__launch_bounds__(256)
__global__ void mfma_gemm(const unsigned short* __restrict__ A1, const unsigned short* __restrict__ B1T,
                          const unsigned short* __restrict__ A2, const unsigned short* __restrict__ B2T,
                          const float* __restrict__ bias,
                          void* __restrict__ Cout, int M, int N, int K) {
    const int tid = threadIdx.x;
    const int w = tid >> 6, lane = tid & 63;
    const int m0 = blockIdx.x * 64, n0 = blockIdx.y * 64;
    const int l15 = lane & 15;
    const int koff = (lane >> 4) * 8;
    const int rowc = min(m0 + w * 16 + l15, M - 1);

    f32x4 acc[4] = {};
#pragma unroll
    for (int pass = 0; pass < PASSES; ++pass) {
        const unsigned short* __restrict__ A  = (PASSES == 2 && pass) ? A2 : A1;
        const unsigned short* __restrict__ BT = (PASSES == 2 && pass) ? B2T : B1T;
        const unsigned short* arow = A + (size_t)rowc * K;
        for (int k0 = 0; k0 < K; k0 += 32) {
            bf16x8 af = *(const bf16x8*)(arow + k0 + koff);
#pragma unroll
            for (int f = 0; f < 4; ++f) {
                const unsigned short* brow = BT + (size_t)(n0 + f * 16 + l15) * K;
                bf16x8 bfr = *(const bf16x8*)(brow + k0 + koff);
                acc[f] = __builtin_amdgcn_mfma_f32_16x16x32_bf16(af, bfr, acc[f], 0, 0, 0);
            }
        }
    }

#pragma unroll
    for (int f = 0; f < 4; ++f) {
        int col = n0 + f * 16 + l15;
        float bv = bias ? bias[col] : 0.f;
#pragma unroll
        for (int r = 0; r < 4; ++r) {
            int grow = m0 + w * 16 + (lane >> 4) * 4 + r;
            if (grow < M) {
                float v = acc[f][r] + bv;
                if (RELU) v = fmaxf(v, 0.f);
                if (OUT_BF16) ((unsigned short*)Cout)[(size_t)grow * N + col] = f2bf(v);
                else          ((float*)Cout)[(size_t)grow * N + col] = v;
            }
        }
    }
}

// ---------------- gemm23: one pass over h -> t (bf16) AND outbase (f32) ----------------
__launch_bounds__(256)
__global__ void gemm23_kernel(const unsigned short* __restrict__ A,
                              const unsigned short* __restrict__ BnT,
                              const unsigned short* __restrict__ BsT,
                              unsigned short* __restrict__ t, float* __restrict__ outbase,
                              int M, int N, int K) {
    const int tid = threadIdx.x;
    const int w = tid >> 6, lane = tid & 63;
    const int m0 = blockIdx.x * 64, n0 = blockIdx.y * 64;
    const int l15 = lane & 15;
    const int koff = (lane >> 4) * 8;
    const int rowc = min(m0 + w * 16 + l15, M - 1);

    f32x4 accn[4] = {};
    f32x4 accs[4] = {};
    const unsigned short* arow = A + (size_t)rowc * K;
    for (int k0 = 0; k0 < K; k0 += 32) {
        bf16x8 af = *(const bf16x8*)(arow + k0 + koff);
#pragma unroll
        for (int f = 0; f < 4; ++f) {
            const unsigned short* bnrow = BnT + (size_t)(n0 + f * 16 + l15) * K;
            const unsigned short* bsrow = BsT + (size_t)(n0 + f * 16 + l15) * K;
            bf16x8 bn = *(const bf16x8*)(bnrow + k0 + koff);
            bf16x8 bs = *(const bf16x8*)(bsrow + k0 + koff);
            accn[f] = __builtin_amdgcn_mfma_f32_16x16x32_bf16(af, bn, accn[f], 0, 0, 0);
            accs[f] = __builtin_amdgcn_mfma_f32_16x16x32_bf16(af, bs, accs[f], 0, 0, 0);
        }
    }

#pragma unroll
    for (int f = 0; f < 4; ++f) {
        int col = n0 + f * 16 + l15;
#pragma unroll
        for (int r = 0; r < 4; ++r) {
            int grow = m0 + w * 16 + (lane >> 4) * 4 + r;
            if (grow < M) {
                t[(size_t)grow * N + col]       = f2bf(accn[f][r]);
                outbase[(size_t)grow * N + col] = accs[f][r];
            }
        }
    }
}

// ---------------- aggadd (8-load ILP): out = (outbase+b2) + invdeg*sum t ------------
__global__ __launch_bounds__(64)
void aggadd_kernel(const unsigned short* __restrict__ t, const int* __restrict__ sorted_src,
                   const int* __restrict__ off, const float* __restrict__ invdeg,
                   const float* __restrict__ outbase, const float* __restrict__ bias,
                   float* __restrict__ out) {
    const int n = blockIdx.x;
    const int lane = threadIdx.x;
    const int s0 = off[n], s1 = off[n + 1];
    __shared__ int sidx[64];
    float a0 = 0.f, b0 = 0.f, a1 = 0.f, b1 = 0.f;
    float a2 = 0.f, b2v = 0.f, a3 = 0.f, b3 = 0.f;
    for (int base = s0; base < s1; base += 64) {
        sidx[lane] = sorted_src[min(base + lane, s1 - 1)];
        __syncthreads();
        int c = min(64, s1 - base);
        int i = 0;
        for (; i + 8 <= c; i += 8) {
            unsigned int u0 = *(const unsigned int*)&t[(size_t)sidx[i + 0] * 128 + 2 * lane];
            unsigned int u1 = *(const unsigned int*)&t[(size_t)sidx[i + 1] * 128 + 2 * lane];
            unsigned int u2 = *(const unsigned int*)&t[(size_t)sidx[i + 2] * 128 + 2 * lane];
            unsigned int u3 = *(const unsigned int*)&t[(size_t)sidx[i + 3] * 128 + 2 * lane];
            unsigned int u4 = *(const unsigned int*)&t[(size_t)sidx[i + 4] * 128 + 2 * lane];
            unsigned int u5 = *(const unsigned int*)&t[(size_t)sidx[i + 5] * 128 + 2 * lane];
            unsigned int u6 = *(const unsigned int*)&t[(size_t)sidx[i + 6] * 128 + 2 * lane];
            unsigned int u7 = *(const unsigned int*)&t[(size_t)sidx[i + 7] * 128 + 2 * lane];
            a0 += bflo(u0); b0 += bfhi(u0);
            a1 += bflo(u1); b1 += bfhi(u1);
            a2 += bflo(u2); b2v += bfhi(u2);
            a3 += bflo(u3); b3 += bfhi(u3);
            a0 += bflo(u4); b0 += bfhi(u4);
            a1 += bflo(u5); b1 += bfhi(u5);
            a2 += bflo(u6); b2v += bfhi(u6);
            a3 += bflo(u7); b3 += bfhi(u7);
        }
        for (; i < c; ++i) {
            unsigned int u = *(const unsigned int*)&t[(size_t)sidx[i] * 128 + 2 * lane];
            a0 += bflo(u); b0 += bfhi(u);
        }
        __syncthreads();
    }
    float inv = invdeg[n];
    float slo = ((a0 + a1) + (a2 + a3)) * inv;
    float shi = ((b0 + b1) + (b2v + b3)) * inv;
    float2 ob = *(const float2*)&outbase[(size_t)n * 128 + 2 * lane];
    float2 o;
    o.x = (ob.x + bias[2 * lane])     + slo;
    o.y = (ob.y + bias[2 * lane + 1]) + shi;
    *(float2*)&out[(size_t)n * 128 + 2 * lane] = o;
}

extern "C" void kernel_launch(void* const* d_in, const int* in_sizes, int n_in,
                              void* d_out, int out_size, void* d_ws, size_t ws_size,
                              hipStream_t stream) {
    const float* x        = (const float*)d_in[0];
    const float* w_self1  = (const float*)d_in[1];
    const float* w_neigh1 = (const float*)d_in[2];
    const float* b1       = (const float*)d_in[3];
    const float* w_self2  = (const float*)d_in[4];
    const float* w_neigh2 = (const float*)d_in[5];
    const float* b2       = (const float*)d_in[6];
    const int*   src      = (const int*)d_in[7];
    const int*   dst      = (const int*)d_in[8];
    float* out = (float*)d_out;

    // workspace layout, 1 KiB-aligned regions
    char* p = (char*)d_ws;
    auto alloc = [&](size_t bytes) { char* q = p; p += (bytes + 1023) & ~(size_t)1023; return q; };
    int*            cntAT      = (int*)alloc(NBUCK * NBLKA * 4);
    int*            runoffT    = (int*)alloc(NBUCK * NBLKA * 4);
    int*            edges      = (int*)alloc((size_t)N_EDGES * 4);   // packed (src<<7)|(dst&127)
    int*            off        = (int*)alloc((NPAD + 1) * 4);
    int*            sorted_src = (int*)alloc((size_t)N_EDGES * 4);
    float*          invdeg     = (float*)alloc(NPAD * 4);
    unsigned short* xb         = (unsigned short*)alloc((size_t)N_NODES * DIM_IN * 2);
    unsigned short* w1sT       = (unsigned short*)alloc(DIM_IN * DIM_HID * 2);
    unsigned short* w1nT       = (unsigned short*)alloc(DIM_IN * DIM_HID * 2);
    unsigned short* w2sT       = (unsigned short*)alloc(DIM_HID * DIM_OUT * 2);
    unsigned short* w2nT       = (unsigned short*)alloc(DIM_HID * DIM_OUT * 2);
    unsigned short* aggbuf     = (unsigned short*)alloc((size_t)N_NODES * 128 * 2);
    unsigned short* h          = (unsigned short*)alloc((size_t)N_NODES * DIM_HID * 2);
    unsigned short* t          = (unsigned short*)alloc((size_t)N_NODES * DIM_OUT * 2);
    float*          outbase    = (float*)alloc((size_t)N_NODES * DIM_OUT * 4);

    // ---- prep (cvt + wtrans) fused with countA ----
    prepc_kernel<<<1250 + 512 + NBLKA, 256, 0, stream>>>(
        x, xb, w_self1, w_neigh1, w_self2, w_neigh2, w1sT, w1nT, w2sT, w2nT, dst, cntAT);

    // ---- CSR build ----
    scanB_kernel   <<<1, 64, 0, stream>>>(cntAT, runoffT);
    scatterA_kernel<<<NBLKA, 256, 0, stream>>>(src, dst, runoffT, edges);
    binB_kernel    <<<NBUCK, 256, 0, stream>>>(edges, runoffT, off, invdeg, sorted_src);

    // ---- layer 1: h = relu(x@Ws1 + agg(x)@Wn1 + b1) ----
    agg_kernel<<<N_NODES, 64, 0, stream>>>(xb, sorted_src, off, invdeg, aggbuf);
    mfma_gemm<2, true, true><<<dim3(157, DIM_HID / 64), 256, 0, stream>>>(
        xb, w1sT, aggbuf, w1nT, b1, h, N_NODES, DIM_HID, DIM_IN);

    // ---- layer 2: {t, outbase} = h@{Wn2, Ws2} one pass; out = (outbase+b2)+agg(t) ----
    gemm23_kernel<<<dim3(157, DIM_OUT / 64), 256, 0, stream>>>(
        h, w2nT, w2sT, t, outbase, N_NODES, DIM_OUT, DIM_HID);
    aggadd_kernel<<<N_NODES, 64, 0, stream>>>(t, sorted_src, off, invdeg, outbase, b2, out);
}